// Round 9
// baseline (373.548 us; speedup 1.0000x reference)
//
#include <hip/hip_runtime.h>
#include <math.h>

typedef float  f32x4  __attribute__((ext_vector_type(4)));
typedef short  bf16x8 __attribute__((ext_vector_type(8)));
typedef unsigned short u16x8 __attribute__((ext_vector_type(8)));

#define XROW 136   // padded LDS row stride in bf16 elems (272 B): breaks 32-way bank conflict

__device__ __forceinline__ float sigmoidf_(float v) {
    return 1.f / (1.f + __expf(-v));
}
__device__ __forceinline__ unsigned short f2b(float f) {
    union { float f; unsigned u; } c; c.f = f;
    const unsigned r = c.u + 0x7FFF + ((c.u >> 16) & 1);   // round-to-nearest-even
    return (unsigned short)(r >> 16);
}
__device__ __forceinline__ float b2f(unsigned short u) {
    union { unsigned u; float f; } c; c.u = ((unsigned)u) << 16;
    return c.f;
}

// Fused prep: blocks [0,192) convert W to bf16 Wt[m][n][k]; blocks >=192 histogram degrees.
__global__ __launch_bounds__(256) void prep_hist(
    const float* __restrict__ Win, const float* __restrict__ Wout,
    const float* __restrict__ Wloop, unsigned short* __restrict__ Wt,
    const int* __restrict__ ei, int* __restrict__ cnt, int N, int E_hist, int E)
{
    if (blockIdx.x < 192) {
        const int t = blockIdx.x * 256 + threadIdx.x;
        if (t >= 3 * 16384) return;
        const int m = t >> 14;
        const int i = t & 16383;           // k*128 + n (coalesced read)
        const int k = i >> 7, n = i & 127;
        const float* W = (m == 0) ? Win : ((m == 1) ? Wout : Wloop);
        Wt[m * 16384 + n * 128 + k] = f2b(W[i]);
    } else {
        const int e = (blockIdx.x - 192) * 256 + threadIdx.x;
        if (e < E_hist) {
            atomicAdd(cnt + ei[E + e], 1);       // in-direction keyed by dst
            atomicAdd(cnt + N + ei[e], 1);       // out-direction keyed by src
        }
    }
}

// Phase 1 (MFMA): 128 nodes/block, 4 waves, 32 nodes/wave.
__global__ __launch_bounds__(256) void sgcn_node_mfma(
    const float* __restrict__ x,
    const unsigned short* __restrict__ Wt,
    const float* __restrict__ b_loop,
    const float* __restrict__ W_loop_g, const float* __restrict__ b_loop_g,
    const float* __restrict__ W_in_g, const float* __restrict__ b_in_g,
    const float* __restrict__ W_out_g, const float* __restrict__ b_out_g,
    unsigned short* __restrict__ h_in, unsigned short* __restrict__ h_out,
    float* __restrict__ sg_in, float* __restrict__ sg_out,
    float* __restrict__ out, int N)
{
    __shared__ unsigned short xs[128 * XROW];   // ~34.8 KB
    __shared__ float gls[128];
    const int tid = threadIdx.x;
    const int n0 = blockIdx.x * 128;

    {
        const int row = tid >> 1;
        const int cb = (tid & 1) * 64;
        unsigned short* dst = &xs[row * XROW + cb];
        const int n = n0 + row;
        if (n < N) {
            const float* xr = x + (size_t)n * 128 + cb;
            #pragma unroll
            for (int i = 0; i < 64; i += 8) {
                const float4 v0 = *(const float4*)(xr + i);
                const float4 v1 = *(const float4*)(xr + i + 4);
                u16x8 pk;
                pk[0] = f2b(v0.x); pk[1] = f2b(v0.y); pk[2] = f2b(v0.z); pk[3] = f2b(v0.w);
                pk[4] = f2b(v1.x); pk[5] = f2b(v1.y); pk[6] = f2b(v1.z); pk[7] = f2b(v1.w);
                *(u16x8*)(dst + i) = pk;
            }
        } else {
            const u16x8 z = {0,0,0,0,0,0,0,0};
            #pragma unroll
            for (int i = 0; i < 64; i += 8) *(u16x8*)(dst + i) = z;
        }
    }
    __syncthreads();

    if (tid < 128) {
        const int n = n0 + tid;
        if (n < N) {
            float gl = 0.f, gi = 0.f, go = 0.f;
            const unsigned short* xr = &xs[tid * XROW];
            for (int kc = 0; kc < 128; kc += 8) {
                const u16x8 c = *(const u16x8*)(xr + kc);
                #pragma unroll
                for (int j = 0; j < 8; ++j) {
                    const float xv = b2f(c[j]);
                    gl = fmaf(xv, W_loop_g[kc + j], gl);
                    gi = fmaf(xv, W_in_g[kc + j], gi);
                    go = fmaf(xv, W_out_g[kc + j], go);
                }
            }
            gls[tid] = sigmoidf_(gl + b_loop_g[0]);
            #pragma unroll
            for (int l = 0; l < 4; ++l) {
                sg_in[(size_t)n * 4 + l]  = sigmoidf_(gi + b_in_g[l]);
                sg_out[(size_t)n * 4 + l] = sigmoidf_(go + b_out_g[l]);
            }
        } else {
            gls[tid] = 0.f;
        }
    }
    __syncthreads();

    const int w  = tid >> 6;
    const int l  = tid & 63;
    const int lr = l & 15;
    const int lk = l >> 4;
    const int rbase = w * 32;

    const unsigned short* a0p = &xs[(rbase + lr) * XROW + lk * 8];
    const unsigned short* a1p = &xs[(rbase + 16 + lr) * XROW + lk * 8];

    for (int ph = 0; ph < 3; ++ph) {
        const unsigned short* Wp = Wt + (size_t)ph * 16384;
        f32x4 acc[2][8];
        #pragma unroll
        for (int p = 0; p < 2; ++p)
            #pragma unroll
            for (int nt = 0; nt < 8; ++nt)
                acc[p][nt] = (f32x4){0.f, 0.f, 0.f, 0.f};

        #pragma unroll
        for (int ks = 0; ks < 4; ++ks) {
            const bf16x8 a0 = *(const bf16x8*)(a0p + ks * 32);
            const bf16x8 a1 = *(const bf16x8*)(a1p + ks * 32);
            #pragma unroll
            for (int nt = 0; nt < 8; ++nt) {
                const bf16x8 b = *(const bf16x8*)(Wp + (nt * 16 + lr) * 128 + ks * 32 + lk * 8);
                acc[0][nt] = __builtin_amdgcn_mfma_f32_16x16x32_bf16(a0, b, acc[0][nt], 0, 0, 0);
                acc[1][nt] = __builtin_amdgcn_mfma_f32_16x16x32_bf16(a1, b, acc[1][nt], 0, 0, 0);
            }
        }

        if (ph < 2) {
            unsigned short* hp = (ph == 0) ? h_in : h_out;
            #pragma unroll
            for (int p = 0; p < 2; ++p)
                #pragma unroll
                for (int r = 0; r < 4; ++r) {
                    const int node = n0 + rbase + p * 16 + lk * 4 + r;
                    if (node < N) {
                        unsigned short* row = hp + (size_t)node * 128 + lr;
                        #pragma unroll
                        for (int nt = 0; nt < 8; ++nt)
                            row[nt * 16] = f2b(acc[p][nt][r]);
                    }
                }
        } else {
            #pragma unroll
            for (int p = 0; p < 2; ++p)
                #pragma unroll
                for (int r = 0; r < 4; ++r) {
                    const int node = n0 + rbase + p * 16 + lk * 4 + r;
                    if (node < N) {
                        const float g = gls[rbase + p * 16 + lk * 4 + r];
                        float* row = out + (size_t)node * 128 + lr;
                        #pragma unroll
                        for (int nt = 0; nt < 8; ++nt)
                            row[nt * 16] = g * (acc[p][nt][r] + b_loop[nt * 16 + lr]);
                    }
                }
        }
    }
}

// ---------- hierarchical scan ----------
__global__ __launch_bounds__(256) void scan_partial(
    const int* __restrict__ cnt, int* __restrict__ bsum, int M)
{
    const int t = threadIdx.x;
    const int base = blockIdx.x * 1024 + t * 4;
    int s = 0;
    if (base + 3 < M) {
        const int4 q = *(const int4*)(cnt + base);
        s = q.x + q.y + q.z + q.w;
    } else {
        for (int i = 0; i < 4; ++i) if (base + i < M) s += cnt[base + i];
    }
    #pragma unroll
    for (int off = 32; off; off >>= 1) s += __shfl_down(s, off, 64);
    __shared__ int red[4];
    if ((t & 63) == 0) red[t >> 6] = s;
    __syncthreads();
    if (t == 0) bsum[blockIdx.x] = red[0] + red[1] + red[2] + red[3];
}

__global__ __launch_bounds__(256) void scan_bsums(int* __restrict__ bsum, int B)
{
    __shared__ int part[256];
    const int t = threadIdx.x;
    const int K = (B + 255) / 256;
    const int lo = t * K;
    const int hi = min(lo + K, B);
    int s = 0;
    for (int i = lo; i < hi; ++i) s += bsum[i];
    part[t] = s;
    __syncthreads();
    for (int off = 1; off < 256; off <<= 1) {
        const int v = (t >= off) ? part[t - off] : 0;
        __syncthreads();
        part[t] += v;
        __syncthreads();
    }
    int run = (t > 0) ? part[t - 1] : 0;
    for (int i = lo; i < hi; ++i) {
        const int c = bsum[i];
        bsum[i] = run;
        run += c;
    }
}

__global__ __launch_bounds__(256) void scan_final(
    int* __restrict__ cnt, const int* __restrict__ bsum,
    int* __restrict__ row_in, int* __restrict__ row_out, int N, int E)
{
    const int t = threadIdx.x;
    const int base = blockIdx.x * 1024 + t * 4;
    const int M = 2 * N;
    int v0 = 0, v1 = 0, v2 = 0, v3 = 0;
    if (base + 3 < M) {
        const int4 q = *(const int4*)(cnt + base);
        v0 = q.x; v1 = q.y; v2 = q.z; v3 = q.w;
    } else {
        if (base     < M) v0 = cnt[base];
        if (base + 1 < M) v1 = cnt[base + 1];
        if (base + 2 < M) v2 = cnt[base + 2];
        if (base + 3 < M) v3 = cnt[base + 3];
    }
    const int s = v0 + v1 + v2 + v3;
    const int lane = t & 63;
    int inc = s;
    #pragma unroll
    for (int off = 1; off < 64; off <<= 1) {
        const int u = __shfl_up(inc, off, 64);
        if (lane >= off) inc += u;
    }
    __shared__ int wsum[4];
    if (lane == 63) wsum[t >> 6] = inc;
    __syncthreads();
    int wpre = 0;
    const int w = t >> 6;
    for (int i = 0; i < w; ++i) wpre += wsum[i];
    int run = bsum[blockIdx.x] + wpre + (inc - s);
    const int vv[4] = {v0, v1, v2, v3};
    #pragma unroll
    for (int i = 0; i < 4; ++i) {
        const int g = base + i;
        if (g < M) {
            if (g < N) row_in[g] = run; else row_out[g - N] = run;
            cnt[g] = run;
            run += vv[i];
        }
    }
    if (blockIdx.x == 0 && t == 0) { row_in[N] = E; row_out[N] = 2 * E; }
}

__global__ __launch_bounds__(256) void sgcn_fill(
    const int* __restrict__ ei, const int* __restrict__ lab,
    int* __restrict__ fill, int* __restrict__ idx, int N, int E)
{
    const int e = blockIdx.x * blockDim.x + threadIdx.x;
    if (e < E) {
        const int s = ei[e];
        const int d = ei[E + e];
        const int l = lab[e];
        const int pi = atomicAdd(fill + d, 1);
        idx[pi] = s * 4 + l;
        const int po = atomicAdd(fill + N + s, 1);
        idx[po] = d * 4 + l;
    }
}

// Phase 2 (CSR): one wave per node; 8 groups of 8 lanes. Groups 0-3 walk the
// in-direction (stride 4), groups 4-7 the out-direction, concurrently -> 8
// independent gather chains in flight, trips = max(din,dout)/4.
// Label-bias factored: sum_e g*(h+b_l) = sum_e g*h + sum_l (sum g_l) * b_l.
__global__ __launch_bounds__(256) void sgcn_gather8(
    const unsigned short* __restrict__ h_in, const unsigned short* __restrict__ h_out,
    const float* __restrict__ sg_in, const float* __restrict__ sg_out,
    const int* __restrict__ row_in, const int* __restrict__ row_out,
    const int* __restrict__ idx,
    const float* __restrict__ b_in, const float* __restrict__ b_out,
    float* __restrict__ out, int N)
{
    const int lane = threadIdx.x & 63;
    const int node = (int)((blockIdx.x * (unsigned)blockDim.x + threadIdx.x) >> 6);
    if (node >= N) return;
    const int grp  = lane >> 3;        // 0..7
    const int dirg = grp >> 2;         // 0 = in, 1 = out
    const int sub  = grp & 3;          // position within direction (stride 4)
    const int sl   = lane & 7;
    const int cb0  = sl * 8;           // cols [cb0, cb0+8)
    const int cb1  = 64 + sl * 8;      // cols [cb1, cb1+8)

    const unsigned short* __restrict__ hp  = dirg ? h_out  : h_in;
    const float*          __restrict__ sgp = dirg ? sg_out : sg_in;
    const int*            __restrict__ rp  = dirg ? row_out : row_in;

    int e        = rp[node] + sub;
    const int e1 = rp[node + 1];

    float acc0[8], acc1[8];
    #pragma unroll
    for (int j = 0; j < 8; ++j) { acc0[j] = 0.f; acc1[j] = 0.f; }
    float ga0 = 0.f, ga1 = 0.f, ga2 = 0.f, ga3 = 0.f;

    for (; e < e1; e += 4) {
        const int p = idx[e];
        const float g = sgp[p];
        const unsigned short* hr = hp + (size_t)(p >> 2) * 128;
        const u16x8 hv0 = *(const u16x8*)(hr + cb0);
        const u16x8 hv1 = *(const u16x8*)(hr + cb1);
        const int l = p & 3;
        ga0 += (l == 0) ? g : 0.f;
        ga1 += (l == 1) ? g : 0.f;
        ga2 += (l == 2) ? g : 0.f;
        ga3 += (l == 3) ? g : 0.f;
        #pragma unroll
        for (int j = 0; j < 8; ++j) {
            acc0[j] = fmaf(g, b2f(hv0[j]), acc0[j]);
            acc1[j] = fmaf(g, b2f(hv1[j]), acc1[j]);
        }
    }

    // split gate sums by direction (other direction contributes zero)
    float gi0 = dirg ? 0.f : ga0, gi1 = dirg ? 0.f : ga1;
    float gi2 = dirg ? 0.f : ga2, gi3 = dirg ? 0.f : ga3;
    float go0 = dirg ? ga0 : 0.f, go1 = dirg ? ga1 : 0.f;
    float go2 = dirg ? ga2 : 0.f, go3 = dirg ? ga3 : 0.f;

    // reduce across the 8 groups: xor8 and xor16 combine within-direction,
    // xor32 merges the two directions.
    #pragma unroll
    for (int j = 0; j < 8; ++j) {
        acc0[j] += __shfl_xor(acc0[j], 8, 64);
        acc0[j] += __shfl_xor(acc0[j], 16, 64);
        acc0[j] += __shfl_xor(acc0[j], 32, 64);
        acc1[j] += __shfl_xor(acc1[j], 8, 64);
        acc1[j] += __shfl_xor(acc1[j], 16, 64);
        acc1[j] += __shfl_xor(acc1[j], 32, 64);
    }
    gi0 += __shfl_xor(gi0, 8, 64); gi0 += __shfl_xor(gi0, 16, 64); gi0 += __shfl_xor(gi0, 32, 64);
    gi1 += __shfl_xor(gi1, 8, 64); gi1 += __shfl_xor(gi1, 16, 64); gi1 += __shfl_xor(gi1, 32, 64);
    gi2 += __shfl_xor(gi2, 8, 64); gi2 += __shfl_xor(gi2, 16, 64); gi2 += __shfl_xor(gi2, 32, 64);
    gi3 += __shfl_xor(gi3, 8, 64); gi3 += __shfl_xor(gi3, 16, 64); gi3 += __shfl_xor(gi3, 32, 64);
    go0 += __shfl_xor(go0, 8, 64); go0 += __shfl_xor(go0, 16, 64); go0 += __shfl_xor(go0, 32, 64);
    go1 += __shfl_xor(go1, 8, 64); go1 += __shfl_xor(go1, 16, 64); go1 += __shfl_xor(go1, 32, 64);
    go2 += __shfl_xor(go2, 8, 64); go2 += __shfl_xor(go2, 16, 64); go2 += __shfl_xor(go2, 32, 64);
    go3 += __shfl_xor(go3, 8, 64); go3 += __shfl_xor(go3, 16, 64); go3 += __shfl_xor(go3, 32, 64);

    if (grp == 0) {   // lanes 0..7 hold the full sums
        const float gis[4] = {gi0, gi1, gi2, gi3};
        const float gos[4] = {go0, go1, go2, go3};
        #pragma unroll
        for (int l = 0; l < 4; ++l) {
            const float4 bia = *(const float4*)(b_in + l * 128 + cb0);
            const float4 bib = *(const float4*)(b_in + l * 128 + cb0 + 4);
            const float4 bic = *(const float4*)(b_in + l * 128 + cb1);
            const float4 bid = *(const float4*)(b_in + l * 128 + cb1 + 4);
            const float4 boa = *(const float4*)(b_out + l * 128 + cb0);
            const float4 bob = *(const float4*)(b_out + l * 128 + cb0 + 4);
            const float4 boc = *(const float4*)(b_out + l * 128 + cb1);
            const float4 bod = *(const float4*)(b_out + l * 128 + cb1 + 4);
            acc0[0] = fmaf(gis[l], bia.x, fmaf(gos[l], boa.x, acc0[0]));
            acc0[1] = fmaf(gis[l], bia.y, fmaf(gos[l], boa.y, acc0[1]));
            acc0[2] = fmaf(gis[l], bia.z, fmaf(gos[l], boa.z, acc0[2]));
            acc0[3] = fmaf(gis[l], bia.w, fmaf(gos[l], boa.w, acc0[3]));
            acc0[4] = fmaf(gis[l], bib.x, fmaf(gos[l], bob.x, acc0[4]));
            acc0[5] = fmaf(gis[l], bib.y, fmaf(gos[l], bob.y, acc0[5]));
            acc0[6] = fmaf(gis[l], bib.z, fmaf(gos[l], bob.z, acc0[6]));
            acc0[7] = fmaf(gis[l], bib.w, fmaf(gos[l], bob.w, acc0[7]));
            acc1[0] = fmaf(gis[l], bic.x, fmaf(gos[l], boc.x, acc1[0]));
            acc1[1] = fmaf(gis[l], bic.y, fmaf(gos[l], boc.y, acc1[1]));
            acc1[2] = fmaf(gis[l], bic.z, fmaf(gos[l], boc.z, acc1[2]));
            acc1[3] = fmaf(gis[l], bic.w, fmaf(gos[l], boc.w, acc1[3]));
            acc1[4] = fmaf(gis[l], bid.x, fmaf(gos[l], bod.x, acc1[4]));
            acc1[5] = fmaf(gis[l], bid.y, fmaf(gos[l], bod.y, acc1[5]));
            acc1[6] = fmaf(gis[l], bid.z, fmaf(gos[l], bod.z, acc1[6]));
            acc1[7] = fmaf(gis[l], bid.w, fmaf(gos[l], bod.w, acc1[7]));
        }
        float* orow = out + (size_t)node * 128;
        float4 o0 = *(const float4*)(orow + cb0);
        float4 o1 = *(const float4*)(orow + cb0 + 4);
        float4 o2 = *(const float4*)(orow + cb1);
        float4 o3 = *(const float4*)(orow + cb1 + 4);
        o0.x = fmaxf(o0.x + acc0[0], 0.f); o0.y = fmaxf(o0.y + acc0[1], 0.f);
        o0.z = fmaxf(o0.z + acc0[2], 0.f); o0.w = fmaxf(o0.w + acc0[3], 0.f);
        o1.x = fmaxf(o1.x + acc0[4], 0.f); o1.y = fmaxf(o1.y + acc0[5], 0.f);
        o1.z = fmaxf(o1.z + acc0[6], 0.f); o1.w = fmaxf(o1.w + acc0[7], 0.f);
        o2.x = fmaxf(o2.x + acc1[0], 0.f); o2.y = fmaxf(o2.y + acc1[1], 0.f);
        o2.z = fmaxf(o2.z + acc1[2], 0.f); o2.w = fmaxf(o2.w + acc1[3], 0.f);
        o3.x = fmaxf(o3.x + acc1[4], 0.f); o3.y = fmaxf(o3.y + acc1[5], 0.f);
        o3.z = fmaxf(o3.z + acc1[6], 0.f); o3.w = fmaxf(o3.w + acc1[7], 0.f);
        *(float4*)(orow + cb0)     = o0;
        *(float4*)(orow + cb0 + 4) = o1;
        *(float4*)(orow + cb1)     = o2;
        *(float4*)(orow + cb1 + 4) = o3;
    }
}

// ---------- fallback (atomic path) ----------
__global__ __launch_bounds__(256) void sgcn_scatter(
    const unsigned short* __restrict__ h_in, const unsigned short* __restrict__ h_out,
    const float* __restrict__ sg_in, const float* __restrict__ sg_out,
    const int* __restrict__ ei, const int* __restrict__ lab,
    const float* __restrict__ b_in, const float* __restrict__ b_out,
    float* __restrict__ out, int E)
{
    const int lane = threadIdx.x & 63;
    const int wid = (blockIdx.x * blockDim.x + threadIdx.x) >> 6;
    const int nw = (gridDim.x * blockDim.x) >> 6;
    const int c = lane * 2;

    for (int e = wid; e < E; e += nw) {
        const int s = ei[e];
        const int d = ei[E + e];
        const int l = lab[e];
        {
            const ushort2 hv = *(const ushort2*)(h_in + (size_t)s * 128 + c);
            const float2 bv = *(const float2*)(b_in + l * 128 + c);
            const float g = sg_in[(size_t)s * 4 + l];
            atomicAdd(out + (size_t)d * 128 + c,     g * (b2f(hv.x) + bv.x));
            atomicAdd(out + (size_t)d * 128 + c + 1, g * (b2f(hv.y) + bv.y));
        }
        {
            const ushort2 hv = *(const ushort2*)(h_out + (size_t)d * 128 + c);
            const float2 bv = *(const float2*)(b_out + l * 128 + c);
            const float g = sg_out[(size_t)d * 4 + l];
            atomicAdd(out + (size_t)s * 128 + c,     g * (b2f(hv.x) + bv.x));
            atomicAdd(out + (size_t)s * 128 + c + 1, g * (b2f(hv.y) + bv.y));
        }
    }
}

__global__ __launch_bounds__(256) void sgcn_relu(float* __restrict__ out, long total4)
{
    const long i = (long)blockIdx.x * blockDim.x + threadIdx.x;
    if (i < total4) {
        float4 v = ((float4*)out)[i];
        v.x = fmaxf(v.x, 0.f); v.y = fmaxf(v.y, 0.f);
        v.z = fmaxf(v.z, 0.f); v.w = fmaxf(v.w, 0.f);
        ((float4*)out)[i] = v;
    }
}

extern "C" void kernel_launch(void* const* d_in, const int* in_sizes, int n_in,
                              void* d_out, int out_size, void* d_ws, size_t ws_size,
                              hipStream_t stream)
{
    const float* x        = (const float*)d_in[0];
    const int*   ei       = (const int*)d_in[1];
    const int*   lab      = (const int*)d_in[2];
    const float* W_loop   = (const float*)d_in[3];
    const float* b_loop   = (const float*)d_in[4];
    const float* W_loop_g = (const float*)d_in[5];
    const float* b_loop_g = (const float*)d_in[6];
    const float* W_in     = (const float*)d_in[7];
    const float* b_in     = (const float*)d_in[8];
    const float* W_in_g   = (const float*)d_in[9];
    const float* b_in_g   = (const float*)d_in[10];
    const float* W_out    = (const float*)d_in[11];
    const float* b_out    = (const float*)d_in[12];
    const float* W_out_g  = (const float*)d_in[13];
    const float* b_out_g  = (const float*)d_in[14];

    const int N = in_sizes[0] / 128;
    const int E = in_sizes[1] / 2;
    const int M = 2 * N;
    const int B = (M + 1023) / 1024;

    unsigned short* h_in  = (unsigned short*)d_ws;            // N*128 bf16
    unsigned short* h_out = h_in + (size_t)N * 128;           // N*128 bf16
    float* sg_in  = (float*)(h_out + (size_t)N * 128);        // N*4
    float* sg_out = sg_in + (size_t)N * 4;                    // N*4
    unsigned short* Wt = (unsigned short*)(sg_out + (size_t)N * 4);  // 3*16384 bf16
    int* row_in  = (int*)(Wt + 3 * 16384);                    // N+1
    int* row_out = row_in + (N + 1);                          // N+1
    int* cnt     = row_out + (N + 1);                         // 2N
    int* bsum    = cnt + M;                                   // B
    int* idx     = bsum + ((B + 3) & ~3);                     // 2E
    const size_t need = ((size_t)(idx + 2 * (size_t)E) - (size_t)d_ws);

    float* out = (float*)d_out;
    dim3 blk(256);
    const bool csr = (need <= ws_size);

    if (csr) hipMemsetAsync(cnt, 0, (size_t)M * sizeof(int), stream);

    const int E_hist = csr ? E : 0;
    const int hist_blocks = csr ? (E + 255) / 256 : 0;
    prep_hist<<<dim3(192 + hist_blocks), blk, 0, stream>>>(
        W_in, W_out, W_loop, Wt, ei, cnt, N, E_hist, E);

    sgcn_node_mfma<<<dim3((N + 127) / 128), blk, 0, stream>>>(
        x, Wt, b_loop, W_loop_g, b_loop_g, W_in_g, b_in_g, W_out_g, b_out_g,
        h_in, h_out, sg_in, sg_out, out, N);

    if (csr) {
        scan_partial<<<dim3(B), blk, 0, stream>>>(cnt, bsum, M);
        scan_bsums<<<dim3(1), blk, 0, stream>>>(bsum, B);
        scan_final<<<dim3(B), blk, 0, stream>>>(cnt, bsum, row_in, row_out, N, E);
        sgcn_fill<<<dim3((E + 255) / 256), blk, 0, stream>>>(ei, lab, cnt, idx, N, E);
        sgcn_gather8<<<dim3((N * 64 + 255) / 256), blk, 0, stream>>>(
            h_in, h_out, sg_in, sg_out, row_in, row_out, idx, b_in, b_out, out, N);
    } else {
        sgcn_scatter<<<dim3(2048), blk, 0, stream>>>(
            h_in, h_out, sg_in, sg_out, ei, lab, b_in, b_out, out, E);
        const long total4 = (long)N * 128 / 4;
        sgcn_relu<<<dim3((unsigned)((total4 + 255) / 256)), blk, 0, stream>>>(out, total4);
    }
}

// Round 10
// 300.070 us; speedup vs baseline: 1.2449x; 1.2449x over previous
//
#include <hip/hip_runtime.h>
#include <math.h>

typedef float  f32x4  __attribute__((ext_vector_type(4)));
typedef short  bf16x8 __attribute__((ext_vector_type(8)));
typedef unsigned short u16x8 __attribute__((ext_vector_type(8)));

#define XROW 136   // padded LDS row stride in bf16 elems (272 B): breaks 32-way bank conflict

__device__ __forceinline__ float sigmoidf_(float v) {
    return 1.f / (1.f + __expf(-v));
}
__device__ __forceinline__ unsigned short f2b(float f) {
    union { float f; unsigned u; } c; c.f = f;
    const unsigned r = c.u + 0x7FFF + ((c.u >> 16) & 1);   // round-to-nearest-even
    return (unsigned short)(r >> 16);
}
__device__ __forceinline__ float b2f(unsigned short u) {
    union { unsigned u; float f; } c; c.u = ((unsigned)u) << 16;
    return c.f;
}

// Fused prep: blocks [0,192) convert W to bf16 Wt[m][n][k]; blocks >=192 histogram degrees.
__global__ __launch_bounds__(256) void prep_hist(
    const float* __restrict__ Win, const float* __restrict__ Wout,
    const float* __restrict__ Wloop, unsigned short* __restrict__ Wt,
    const int* __restrict__ ei, int* __restrict__ cnt, int N, int E_hist, int E)
{
    if (blockIdx.x < 192) {
        const int t = blockIdx.x * 256 + threadIdx.x;
        if (t >= 3 * 16384) return;
        const int m = t >> 14;
        const int i = t & 16383;           // k*128 + n (coalesced read)
        const int k = i >> 7, n = i & 127;
        const float* W = (m == 0) ? Win : ((m == 1) ? Wout : Wloop);
        Wt[m * 16384 + n * 128 + k] = f2b(W[i]);
    } else {
        const int e = (blockIdx.x - 192) * 256 + threadIdx.x;
        if (e < E_hist) {
            atomicAdd(cnt + ei[E + e], 1);       // in-direction keyed by dst
            atomicAdd(cnt + N + ei[e], 1);       // out-direction keyed by src
        }
    }
}

// Phase 1 (MFMA): 128 nodes/block, 4 waves, 32 nodes/wave.
__global__ __launch_bounds__(256) void sgcn_node_mfma(
    const float* __restrict__ x,
    const unsigned short* __restrict__ Wt,
    const float* __restrict__ b_loop,
    const float* __restrict__ W_loop_g, const float* __restrict__ b_loop_g,
    const float* __restrict__ W_in_g, const float* __restrict__ b_in_g,
    const float* __restrict__ W_out_g, const float* __restrict__ b_out_g,
    unsigned short* __restrict__ h_in, unsigned short* __restrict__ h_out,
    float* __restrict__ sg_in, float* __restrict__ sg_out,
    float* __restrict__ out, int N)
{
    __shared__ unsigned short xs[128 * XROW];   // ~34.8 KB
    __shared__ float gls[128];
    const int tid = threadIdx.x;
    const int n0 = blockIdx.x * 128;

    {
        const int row = tid >> 1;
        const int cb = (tid & 1) * 64;
        unsigned short* dst = &xs[row * XROW + cb];
        const int n = n0 + row;
        if (n < N) {
            const float* xr = x + (size_t)n * 128 + cb;
            #pragma unroll
            for (int i = 0; i < 64; i += 8) {
                const float4 v0 = *(const float4*)(xr + i);
                const float4 v1 = *(const float4*)(xr + i + 4);
                u16x8 pk;
                pk[0] = f2b(v0.x); pk[1] = f2b(v0.y); pk[2] = f2b(v0.z); pk[3] = f2b(v0.w);
                pk[4] = f2b(v1.x); pk[5] = f2b(v1.y); pk[6] = f2b(v1.z); pk[7] = f2b(v1.w);
                *(u16x8*)(dst + i) = pk;
            }
        } else {
            const u16x8 z = {0,0,0,0,0,0,0,0};
            #pragma unroll
            for (int i = 0; i < 64; i += 8) *(u16x8*)(dst + i) = z;
        }
    }
    __syncthreads();

    if (tid < 128) {
        const int n = n0 + tid;
        if (n < N) {
            float gl = 0.f, gi = 0.f, go = 0.f;
            const unsigned short* xr = &xs[tid * XROW];
            for (int kc = 0; kc < 128; kc += 8) {
                const u16x8 c = *(const u16x8*)(xr + kc);
                #pragma unroll
                for (int j = 0; j < 8; ++j) {
                    const float xv = b2f(c[j]);
                    gl = fmaf(xv, W_loop_g[kc + j], gl);
                    gi = fmaf(xv, W_in_g[kc + j], gi);
                    go = fmaf(xv, W_out_g[kc + j], go);
                }
            }
            gls[tid] = sigmoidf_(gl + b_loop_g[0]);
            #pragma unroll
            for (int l = 0; l < 4; ++l) {
                sg_in[(size_t)n * 4 + l]  = sigmoidf_(gi + b_in_g[l]);
                sg_out[(size_t)n * 4 + l] = sigmoidf_(go + b_out_g[l]);
            }
        } else {
            gls[tid] = 0.f;
        }
    }
    __syncthreads();

    const int w  = tid >> 6;
    const int l  = tid & 63;
    const int lr = l & 15;
    const int lk = l >> 4;
    const int rbase = w * 32;

    const unsigned short* a0p = &xs[(rbase + lr) * XROW + lk * 8];
    const unsigned short* a1p = &xs[(rbase + 16 + lr) * XROW + lk * 8];

    for (int ph = 0; ph < 3; ++ph) {
        const unsigned short* Wp = Wt + (size_t)ph * 16384;
        f32x4 acc[2][8];
        #pragma unroll
        for (int p = 0; p < 2; ++p)
            #pragma unroll
            for (int nt = 0; nt < 8; ++nt)
                acc[p][nt] = (f32x4){0.f, 0.f, 0.f, 0.f};

        #pragma unroll
        for (int ks = 0; ks < 4; ++ks) {
            const bf16x8 a0 = *(const bf16x8*)(a0p + ks * 32);
            const bf16x8 a1 = *(const bf16x8*)(a1p + ks * 32);
            #pragma unroll
            for (int nt = 0; nt < 8; ++nt) {
                const bf16x8 b = *(const bf16x8*)(Wp + (nt * 16 + lr) * 128 + ks * 32 + lk * 8);
                acc[0][nt] = __builtin_amdgcn_mfma_f32_16x16x32_bf16(a0, b, acc[0][nt], 0, 0, 0);
                acc[1][nt] = __builtin_amdgcn_mfma_f32_16x16x32_bf16(a1, b, acc[1][nt], 0, 0, 0);
            }
        }

        if (ph < 2) {
            unsigned short* hp = (ph == 0) ? h_in : h_out;
            #pragma unroll
            for (int p = 0; p < 2; ++p)
                #pragma unroll
                for (int r = 0; r < 4; ++r) {
                    const int node = n0 + rbase + p * 16 + lk * 4 + r;
                    if (node < N) {
                        unsigned short* row = hp + (size_t)node * 128 + lr;
                        #pragma unroll
                        for (int nt = 0; nt < 8; ++nt)
                            row[nt * 16] = f2b(acc[p][nt][r]);
                    }
                }
        } else {
            #pragma unroll
            for (int p = 0; p < 2; ++p)
                #pragma unroll
                for (int r = 0; r < 4; ++r) {
                    const int node = n0 + rbase + p * 16 + lk * 4 + r;
                    if (node < N) {
                        const float g = gls[rbase + p * 16 + lk * 4 + r];
                        float* row = out + (size_t)node * 128 + lr;
                        #pragma unroll
                        for (int nt = 0; nt < 8; ++nt)
                            row[nt * 16] = g * (acc[p][nt][r] + b_loop[nt * 16 + lr]);
                    }
                }
        }
    }
}

// ---------- hierarchical scan ----------
__global__ __launch_bounds__(256) void scan_partial(
    const int* __restrict__ cnt, int* __restrict__ bsum, int M)
{
    const int t = threadIdx.x;
    const int base = blockIdx.x * 1024 + t * 4;
    int s = 0;
    if (base + 3 < M) {
        const int4 q = *(const int4*)(cnt + base);
        s = q.x + q.y + q.z + q.w;
    } else {
        for (int i = 0; i < 4; ++i) if (base + i < M) s += cnt[base + i];
    }
    #pragma unroll
    for (int off = 32; off; off >>= 1) s += __shfl_down(s, off, 64);
    __shared__ int red[4];
    if ((t & 63) == 0) red[t >> 6] = s;
    __syncthreads();
    if (t == 0) bsum[blockIdx.x] = red[0] + red[1] + red[2] + red[3];
}

__global__ __launch_bounds__(256) void scan_bsums(int* __restrict__ bsum, int B)
{
    __shared__ int part[256];
    const int t = threadIdx.x;
    const int K = (B + 255) / 256;
    const int lo = t * K;
    const int hi = min(lo + K, B);
    int s = 0;
    for (int i = lo; i < hi; ++i) s += bsum[i];
    part[t] = s;
    __syncthreads();
    for (int off = 1; off < 256; off <<= 1) {
        const int v = (t >= off) ? part[t - off] : 0;
        __syncthreads();
        part[t] += v;
        __syncthreads();
    }
    int run = (t > 0) ? part[t - 1] : 0;
    for (int i = lo; i < hi; ++i) {
        const int c = bsum[i];
        bsum[i] = run;
        run += c;
    }
}

__global__ __launch_bounds__(256) void scan_final(
    int* __restrict__ cnt, const int* __restrict__ bsum,
    int* __restrict__ row_in, int* __restrict__ row_out, int N, int E)
{
    const int t = threadIdx.x;
    const int base = blockIdx.x * 1024 + t * 4;
    const int M = 2 * N;
    int v0 = 0, v1 = 0, v2 = 0, v3 = 0;
    if (base + 3 < M) {
        const int4 q = *(const int4*)(cnt + base);
        v0 = q.x; v1 = q.y; v2 = q.z; v3 = q.w;
    } else {
        if (base     < M) v0 = cnt[base];
        if (base + 1 < M) v1 = cnt[base + 1];
        if (base + 2 < M) v2 = cnt[base + 2];
        if (base + 3 < M) v3 = cnt[base + 3];
    }
    const int s = v0 + v1 + v2 + v3;
    const int lane = t & 63;
    int inc = s;
    #pragma unroll
    for (int off = 1; off < 64; off <<= 1) {
        const int u = __shfl_up(inc, off, 64);
        if (lane >= off) inc += u;
    }
    __shared__ int wsum[4];
    if (lane == 63) wsum[t >> 6] = inc;
    __syncthreads();
    int wpre = 0;
    const int w = t >> 6;
    for (int i = 0; i < w; ++i) wpre += wsum[i];
    int run = bsum[blockIdx.x] + wpre + (inc - s);
    const int vv[4] = {v0, v1, v2, v3};
    #pragma unroll
    for (int i = 0; i < 4; ++i) {
        const int g = base + i;
        if (g < M) {
            if (g < N) row_in[g] = run; else row_out[g - N] = run;
            cnt[g] = run;
            run += vv[i];
        }
    }
    if (blockIdx.x == 0 && t == 0) { row_in[N] = E; row_out[N] = 2 * E; }
}

// Fill CSR entries with the gate PACKED alongside the index: idx2[e] = {node*4+label, bits(gate)}.
// sg_* are ready (sgcn_node_mfma runs before this on the stream).
__global__ __launch_bounds__(256) void sgcn_fill(
    const int* __restrict__ ei, const int* __restrict__ lab,
    const float* __restrict__ sg_in, const float* __restrict__ sg_out,
    int* __restrict__ fill, int2* __restrict__ idx2, int N, int E)
{
    const int e = blockIdx.x * blockDim.x + threadIdx.x;
    if (e < E) {
        const int s = ei[e];
        const int d = ei[E + e];
        const int l = lab[e];
        const int pi = atomicAdd(fill + d, 1);        // in [0, E)
        idx2[pi] = make_int2(s * 4 + l, __float_as_int(sg_in[(size_t)s * 4 + l]));
        const int po = atomicAdd(fill + N + s, 1);    // in [E, 2E)
        idx2[po] = make_int2(d * 4 + l, __float_as_int(sg_out[(size_t)d * 4 + l]));
    }
}

// Phase 2 (CSR): one wave per node, 4 edge-groups of 16 lanes (proven shape),
// gate pre-packed in idx2 -> inner loop has ONE random access (the h row).
// Label-bias factored: sum_e g*(h+b_l) = sum_e g*h + sum_l (sum g_l) * b_l.
__global__ __launch_bounds__(256) void sgcn_gather4g(
    const unsigned short* __restrict__ h_in, const unsigned short* __restrict__ h_out,
    const int* __restrict__ row_in, const int* __restrict__ row_out,
    const int2* __restrict__ idx2,
    const float* __restrict__ b_in, const float* __restrict__ b_out,
    float* __restrict__ out, int N)
{
    const int lane = threadIdx.x & 63;
    const int node = (int)((blockIdx.x * (unsigned)blockDim.x + threadIdx.x) >> 6);
    if (node >= N) return;
    const int sub = lane >> 4;      // edge group 0..3
    const int sl  = lane & 15;      // 16 lanes x 8 cols = 128 cols
    const int cb  = sl * 8;

    float acc[8];
    #pragma unroll
    for (int j = 0; j < 8; ++j) acc[j] = 0.f;
    float gi0 = 0.f, gi1 = 0.f, gi2 = 0.f, gi3 = 0.f;
    float go0 = 0.f, go1 = 0.f, go2 = 0.f, go3 = 0.f;

    {
        const int e1 = row_in[node + 1];
        for (int e = row_in[node] + sub; e < e1; e += 4) {
            const int2 pq = idx2[e];
            const float g = __int_as_float(pq.y);
            const u16x8 hv = *(const u16x8*)(h_in + (size_t)(pq.x >> 2) * 128 + cb);
            const int l = pq.x & 3;
            gi0 += (l == 0) ? g : 0.f;
            gi1 += (l == 1) ? g : 0.f;
            gi2 += (l == 2) ? g : 0.f;
            gi3 += (l == 3) ? g : 0.f;
            #pragma unroll
            for (int j = 0; j < 8; ++j) acc[j] = fmaf(g, b2f(hv[j]), acc[j]);
        }
    }
    {
        const int e1 = row_out[node + 1];
        for (int e = row_out[node] + sub; e < e1; e += 4) {
            const int2 pq = idx2[e];
            const float g = __int_as_float(pq.y);
            const u16x8 hv = *(const u16x8*)(h_out + (size_t)(pq.x >> 2) * 128 + cb);
            const int l = pq.x & 3;
            go0 += (l == 0) ? g : 0.f;
            go1 += (l == 1) ? g : 0.f;
            go2 += (l == 2) ? g : 0.f;
            go3 += (l == 3) ? g : 0.f;
            #pragma unroll
            for (int j = 0; j < 8; ++j) acc[j] = fmaf(g, b2f(hv[j]), acc[j]);
        }
    }

    // combine the 4 edge groups (lanes l, l^16, l^32, l^48 share the same cols)
    #pragma unroll
    for (int j = 0; j < 8; ++j) {
        acc[j] += __shfl_xor(acc[j], 16, 64);
        acc[j] += __shfl_xor(acc[j], 32, 64);
    }
    gi0 += __shfl_xor(gi0, 16, 64); gi0 += __shfl_xor(gi0, 32, 64);
    gi1 += __shfl_xor(gi1, 16, 64); gi1 += __shfl_xor(gi1, 32, 64);
    gi2 += __shfl_xor(gi2, 16, 64); gi2 += __shfl_xor(gi2, 32, 64);
    gi3 += __shfl_xor(gi3, 16, 64); gi3 += __shfl_xor(gi3, 32, 64);
    go0 += __shfl_xor(go0, 16, 64); go0 += __shfl_xor(go0, 32, 64);
    go1 += __shfl_xor(go1, 16, 64); go1 += __shfl_xor(go1, 32, 64);
    go2 += __shfl_xor(go2, 16, 64); go2 += __shfl_xor(go2, 32, 64);
    go3 += __shfl_xor(go3, 16, 64); go3 += __shfl_xor(go3, 32, 64);

    if (sub == 0) {
        const float gis[4] = {gi0, gi1, gi2, gi3};
        const float gos[4] = {go0, go1, go2, go3};
        #pragma unroll
        for (int l = 0; l < 4; ++l) {
            const float4 bi0 = *(const float4*)(b_in + l * 128 + cb);
            const float4 bi1 = *(const float4*)(b_in + l * 128 + cb + 4);
            const float4 bo0 = *(const float4*)(b_out + l * 128 + cb);
            const float4 bo1 = *(const float4*)(b_out + l * 128 + cb + 4);
            acc[0] = fmaf(gis[l], bi0.x, fmaf(gos[l], bo0.x, acc[0]));
            acc[1] = fmaf(gis[l], bi0.y, fmaf(gos[l], bo0.y, acc[1]));
            acc[2] = fmaf(gis[l], bi0.z, fmaf(gos[l], bo0.z, acc[2]));
            acc[3] = fmaf(gis[l], bi0.w, fmaf(gos[l], bo0.w, acc[3]));
            acc[4] = fmaf(gis[l], bi1.x, fmaf(gos[l], bo1.x, acc[4]));
            acc[5] = fmaf(gis[l], bi1.y, fmaf(gos[l], bo1.y, acc[5]));
            acc[6] = fmaf(gis[l], bi1.z, fmaf(gos[l], bo1.z, acc[6]));
            acc[7] = fmaf(gis[l], bi1.w, fmaf(gos[l], bo1.w, acc[7]));
        }
        float* orow = out + (size_t)node * 128 + cb;
        float4 o0 = *(const float4*)orow;
        float4 o1 = *(const float4*)(orow + 4);
        o0.x = fmaxf(o0.x + acc[0], 0.f); o0.y = fmaxf(o0.y + acc[1], 0.f);
        o0.z = fmaxf(o0.z + acc[2], 0.f); o0.w = fmaxf(o0.w + acc[3], 0.f);
        o1.x = fmaxf(o1.x + acc[4], 0.f); o1.y = fmaxf(o1.y + acc[5], 0.f);
        o1.z = fmaxf(o1.z + acc[6], 0.f); o1.w = fmaxf(o1.w + acc[7], 0.f);
        *(float4*)orow = o0;
        *(float4*)(orow + 4) = o1;
    }
}

// ---------- fallback (atomic path) ----------
__global__ __launch_bounds__(256) void sgcn_scatter(
    const unsigned short* __restrict__ h_in, const unsigned short* __restrict__ h_out,
    const float* __restrict__ sg_in, const float* __restrict__ sg_out,
    const int* __restrict__ ei, const int* __restrict__ lab,
    const float* __restrict__ b_in, const float* __restrict__ b_out,
    float* __restrict__ out, int E)
{
    const int lane = threadIdx.x & 63;
    const int wid = (blockIdx.x * blockDim.x + threadIdx.x) >> 6;
    const int nw = (gridDim.x * blockDim.x) >> 6;
    const int c = lane * 2;

    for (int e = wid; e < E; e += nw) {
        const int s = ei[e];
        const int d = ei[E + e];
        const int l = lab[e];
        {
            const ushort2 hv = *(const ushort2*)(h_in + (size_t)s * 128 + c);
            const float2 bv = *(const float2*)(b_in + l * 128 + c);
            const float g = sg_in[(size_t)s * 4 + l];
            atomicAdd(out + (size_t)d * 128 + c,     g * (b2f(hv.x) + bv.x));
            atomicAdd(out + (size_t)d * 128 + c + 1, g * (b2f(hv.y) + bv.y));
        }
        {
            const ushort2 hv = *(const ushort2*)(h_out + (size_t)d * 128 + c);
            const float2 bv = *(const float2*)(b_out + l * 128 + c);
            const float g = sg_out[(size_t)d * 4 + l];
            atomicAdd(out + (size_t)s * 128 + c,     g * (b2f(hv.x) + bv.x));
            atomicAdd(out + (size_t)s * 128 + c + 1, g * (b2f(hv.y) + bv.y));
        }
    }
}

__global__ __launch_bounds__(256) void sgcn_relu(float* __restrict__ out, long total4)
{
    const long i = (long)blockIdx.x * blockDim.x + threadIdx.x;
    if (i < total4) {
        float4 v = ((float4*)out)[i];
        v.x = fmaxf(v.x, 0.f); v.y = fmaxf(v.y, 0.f);
        v.z = fmaxf(v.z, 0.f); v.w = fmaxf(v.w, 0.f);
        ((float4*)out)[i] = v;
    }
}

extern "C" void kernel_launch(void* const* d_in, const int* in_sizes, int n_in,
                              void* d_out, int out_size, void* d_ws, size_t ws_size,
                              hipStream_t stream)
{
    const float* x        = (const float*)d_in[0];
    const int*   ei       = (const int*)d_in[1];
    const int*   lab      = (const int*)d_in[2];
    const float* W_loop   = (const float*)d_in[3];
    const float* b_loop   = (const float*)d_in[4];
    const float* W_loop_g = (const float*)d_in[5];
    const float* b_loop_g = (const float*)d_in[6];
    const float* W_in     = (const float*)d_in[7];
    const float* b_in     = (const float*)d_in[8];
    const float* W_in_g   = (const float*)d_in[9];
    const float* b_in_g   = (const float*)d_in[10];
    const float* W_out    = (const float*)d_in[11];
    const float* b_out    = (const float*)d_in[12];
    const float* W_out_g  = (const float*)d_in[13];
    const float* b_out_g  = (const float*)d_in[14];

    const int N = in_sizes[0] / 128;
    const int E = in_sizes[1] / 2;
    const int M = 2 * N;
    const int B = (M + 1023) / 1024;

    unsigned short* h_in  = (unsigned short*)d_ws;            // N*128 bf16
    unsigned short* h_out = h_in + (size_t)N * 128;           // N*128 bf16
    float* sg_in  = (float*)(h_out + (size_t)N * 128);        // N*4
    float* sg_out = sg_in + (size_t)N * 4;                    // N*4
    unsigned short* Wt = (unsigned short*)(sg_out + (size_t)N * 4);  // 3*16384 bf16
    int* row_in  = (int*)(Wt + 3 * 16384);                    // N+1
    int* row_out = row_in + (N + 1);                          // N+1
    int* cnt     = row_out + (N + 1);                         // 2N
    int* bsum    = cnt + M;                                   // B
    int2* idx2   = (int2*)(((size_t)(bsum + B) + 15) & ~(size_t)15);  // 2E int2
    const size_t need = ((size_t)(idx2 + 2 * (size_t)E) - (size_t)d_ws);

    float* out = (float*)d_out;
    dim3 blk(256);
    const bool csr = (need <= ws_size);

    if (csr) hipMemsetAsync(cnt, 0, (size_t)M * sizeof(int), stream);

    const int E_hist = csr ? E : 0;
    const int hist_blocks = csr ? (E + 255) / 256 : 0;
    prep_hist<<<dim3(192 + hist_blocks), blk, 0, stream>>>(
        W_in, W_out, W_loop, Wt, ei, cnt, N, E_hist, E);

    sgcn_node_mfma<<<dim3((N + 127) / 128), blk, 0, stream>>>(
        x, Wt, b_loop, W_loop_g, b_loop_g, W_in_g, b_in_g, W_out_g, b_out_g,
        h_in, h_out, sg_in, sg_out, out, N);

    if (csr) {
        scan_partial<<<dim3(B), blk, 0, stream>>>(cnt, bsum, M);
        scan_bsums<<<dim3(1), blk, 0, stream>>>(bsum, B);
        scan_final<<<dim3(B), blk, 0, stream>>>(cnt, bsum, row_in, row_out, N, E);
        sgcn_fill<<<dim3((E + 255) / 256), blk, 0, stream>>>(
            ei, lab, sg_in, sg_out, cnt, idx2, N, E);
        sgcn_gather4g<<<dim3((N * 64 + 255) / 256), blk, 0, stream>>>(
            h_in, h_out, row_in, row_out, idx2, b_in, b_out, out, N);
    } else {
        sgcn_scatter<<<dim3(2048), blk, 0, stream>>>(
            h_in, h_out, sg_in, sg_out, ei, lab, b_in, b_out, out, E);
        const long total4 = (long)N * 128 / 4;
        sgcn_relu<<<dim3((unsigned)((total4 + 255) / 256)), blk, 0, stream>>>(out, total4);
    }
}

// Round 13
// 291.636 us; speedup vs baseline: 1.2809x; 1.0289x over previous
//
#include <hip/hip_runtime.h>
#include <math.h>

typedef float  f32x4  __attribute__((ext_vector_type(4)));
typedef short  bf16x8 __attribute__((ext_vector_type(8)));
typedef unsigned short u16x8 __attribute__((ext_vector_type(8)));

#define XROW 136   // padded LDS row stride in bf16 elems (272 B): breaks 32-way bank conflict

__device__ __forceinline__ float sigmoidf_(float v) {
    return 1.f / (1.f + __expf(-v));
}
__device__ __forceinline__ unsigned short f2b(float f) {
    union { float f; unsigned u; } c; c.f = f;
    const unsigned r = c.u + 0x7FFF + ((c.u >> 16) & 1);   // round-to-nearest-even
    return (unsigned short)(r >> 16);
}
__device__ __forceinline__ float b2f(unsigned short u) {
    union { unsigned u; float f; } c; c.u = ((unsigned)u) << 16;
    return c.f;
}

// Fused prep: blocks [0,192) convert W to bf16 Wt[m][n][k]; blocks >=192 histogram degrees.
__global__ __launch_bounds__(256) void prep_hist(
    const float* __restrict__ Win, const float* __restrict__ Wout,
    const float* __restrict__ Wloop, unsigned short* __restrict__ Wt,
    const int* __restrict__ ei, int* __restrict__ cnt, int N, int E_hist, int E)
{
    if (blockIdx.x < 192) {
        const int t = blockIdx.x * 256 + threadIdx.x;
        if (t >= 3 * 16384) return;
        const int m = t >> 14;
        const int i = t & 16383;           // k*128 + n (coalesced read)
        const int k = i >> 7, n = i & 127;
        const float* W = (m == 0) ? Win : ((m == 1) ? Wout : Wloop);
        Wt[m * 16384 + n * 128 + k] = f2b(W[i]);
    } else {
        const int e = (blockIdx.x - 192) * 256 + threadIdx.x;
        if (e < E_hist) {
            atomicAdd(cnt + ei[E + e], 1);       // in-direction keyed by dst
            atomicAdd(cnt + N + ei[e], 1);       // out-direction keyed by src
        }
    }
}

// Phase 1 (MFMA): 128 nodes/block, 4 waves, 32 nodes/wave.
__global__ __launch_bounds__(256) void sgcn_node_mfma(
    const float* __restrict__ x,
    const unsigned short* __restrict__ Wt,
    const float* __restrict__ b_loop,
    const float* __restrict__ W_loop_g, const float* __restrict__ b_loop_g,
    const float* __restrict__ W_in_g, const float* __restrict__ b_in_g,
    const float* __restrict__ W_out_g, const float* __restrict__ b_out_g,
    unsigned short* __restrict__ h_in, unsigned short* __restrict__ h_out,
    float* __restrict__ sg_in, float* __restrict__ sg_out,
    float* __restrict__ out, int N)
{
    __shared__ unsigned short xs[128 * XROW];   // ~34.8 KB
    __shared__ float gls[128];
    const int tid = threadIdx.x;
    const int n0 = blockIdx.x * 128;

    {
        const int row = tid >> 1;
        const int cb = (tid & 1) * 64;
        unsigned short* dst = &xs[row * XROW + cb];
        const int n = n0 + row;
        if (n < N) {
            const float* xr = x + (size_t)n * 128 + cb;
            #pragma unroll
            for (int i = 0; i < 64; i += 8) {
                const float4 v0 = *(const float4*)(xr + i);
                const float4 v1 = *(const float4*)(xr + i + 4);
                u16x8 pk;
                pk[0] = f2b(v0.x); pk[1] = f2b(v0.y); pk[2] = f2b(v0.z); pk[3] = f2b(v0.w);
                pk[4] = f2b(v1.x); pk[5] = f2b(v1.y); pk[6] = f2b(v1.z); pk[7] = f2b(v1.w);
                *(u16x8*)(dst + i) = pk;
            }
        } else {
            const u16x8 z = {0,0,0,0,0,0,0,0};
            #pragma unroll
            for (int i = 0; i < 64; i += 8) *(u16x8*)(dst + i) = z;
        }
    }
    __syncthreads();

    if (tid < 128) {
        const int n = n0 + tid;
        if (n < N) {
            float gl = 0.f, gi = 0.f, go = 0.f;
            const unsigned short* xr = &xs[tid * XROW];
            for (int kc = 0; kc < 128; kc += 8) {
                const u16x8 c = *(const u16x8*)(xr + kc);
                #pragma unroll
                for (int j = 0; j < 8; ++j) {
                    const float xv = b2f(c[j]);
                    gl = fmaf(xv, W_loop_g[kc + j], gl);
                    gi = fmaf(xv, W_in_g[kc + j], gi);
                    go = fmaf(xv, W_out_g[kc + j], go);
                }
            }
            gls[tid] = sigmoidf_(gl + b_loop_g[0]);
            #pragma unroll
            for (int l = 0; l < 4; ++l) {
                sg_in[(size_t)n * 4 + l]  = sigmoidf_(gi + b_in_g[l]);
                sg_out[(size_t)n * 4 + l] = sigmoidf_(go + b_out_g[l]);
            }
        } else {
            gls[tid] = 0.f;
        }
    }
    __syncthreads();

    const int w  = tid >> 6;
    const int l  = tid & 63;
    const int lr = l & 15;
    const int lk = l >> 4;
    const int rbase = w * 32;

    const unsigned short* a0p = &xs[(rbase + lr) * XROW + lk * 8];
    const unsigned short* a1p = &xs[(rbase + 16 + lr) * XROW + lk * 8];

    for (int ph = 0; ph < 3; ++ph) {
        const unsigned short* Wp = Wt + (size_t)ph * 16384;
        f32x4 acc[2][8];
        #pragma unroll
        for (int p = 0; p < 2; ++p)
            #pragma unroll
            for (int nt = 0; nt < 8; ++nt)
                acc[p][nt] = (f32x4){0.f, 0.f, 0.f, 0.f};

        #pragma unroll
        for (int ks = 0; ks < 4; ++ks) {
            const bf16x8 a0 = *(const bf16x8*)(a0p + ks * 32);
            const bf16x8 a1 = *(const bf16x8*)(a1p + ks * 32);
            #pragma unroll
            for (int nt = 0; nt < 8; ++nt) {
                const bf16x8 b = *(const bf16x8*)(Wp + (nt * 16 + lr) * 128 + ks * 32 + lk * 8);
                acc[0][nt] = __builtin_amdgcn_mfma_f32_16x16x32_bf16(a0, b, acc[0][nt], 0, 0, 0);
                acc[1][nt] = __builtin_amdgcn_mfma_f32_16x16x32_bf16(a1, b, acc[1][nt], 0, 0, 0);
            }
        }

        if (ph < 2) {
            unsigned short* hp = (ph == 0) ? h_in : h_out;
            #pragma unroll
            for (int p = 0; p < 2; ++p)
                #pragma unroll
                for (int r = 0; r < 4; ++r) {
                    const int node = n0 + rbase + p * 16 + lk * 4 + r;
                    if (node < N) {
                        unsigned short* row = hp + (size_t)node * 128 + lr;
                        #pragma unroll
                        for (int nt = 0; nt < 8; ++nt)
                            row[nt * 16] = f2b(acc[p][nt][r]);
                    }
                }
        } else {
            #pragma unroll
            for (int p = 0; p < 2; ++p)
                #pragma unroll
                for (int r = 0; r < 4; ++r) {
                    const int node = n0 + rbase + p * 16 + lk * 4 + r;
                    if (node < N) {
                        const float g = gls[rbase + p * 16 + lk * 4 + r];
                        float* row = out + (size_t)node * 128 + lr;
                        #pragma unroll
                        for (int nt = 0; nt < 8; ++nt)
                            row[nt * 16] = g * (acc[p][nt][r] + b_loop[nt * 16 + lr]);
                    }
                }
        }
    }
}

// ---------- hierarchical scan (2 kernels) ----------
__global__ __launch_bounds__(256) void scan_partial(
    const int* __restrict__ cnt, int* __restrict__ bsum, int M)
{
    const int t = threadIdx.x;
    const int base = blockIdx.x * 1024 + t * 4;
    int s = 0;
    if (base + 3 < M) {
        const int4 q = *(const int4*)(cnt + base);
        s = q.x + q.y + q.z + q.w;
    } else {
        for (int i = 0; i < 4; ++i) if (base + i < M) s += cnt[base + i];
    }
    #pragma unroll
    for (int off = 32; off; off >>= 1) s += __shfl_down(s, off, 64);
    __shared__ int red[4];
    if ((t & 63) == 0) red[t >> 6] = s;
    __syncthreads();
    if (t == 0) bsum[blockIdx.x] = red[0] + red[1] + red[2] + red[3];
}

// Finalize: each block computes its own prefix over raw bsum[0..blockIdx) (B<=256-ish,
// strided loop handles any B), then the in-block exclusive scan; writes rows + fill cursors.
__global__ __launch_bounds__(256) void scan_final(
    int* __restrict__ cnt, const int* __restrict__ bsum,
    int* __restrict__ row_in, int* __restrict__ row_out, int N, int E)
{
    const int t = threadIdx.x;
    // block prefix = sum of bsum[0..blockIdx.x)
    int pv = 0;
    for (int i = t; i < blockIdx.x; i += 256) pv += bsum[i];
    #pragma unroll
    for (int off = 32; off; off >>= 1) pv += __shfl_down(pv, off, 64);
    __shared__ int pre4[4];
    if ((t & 63) == 0) pre4[t >> 6] = pv;
    __syncthreads();
    const int bpre = pre4[0] + pre4[1] + pre4[2] + pre4[3];

    const int base = blockIdx.x * 1024 + t * 4;
    const int M = 2 * N;
    int v0 = 0, v1 = 0, v2 = 0, v3 = 0;
    if (base + 3 < M) {
        const int4 q = *(const int4*)(cnt + base);
        v0 = q.x; v1 = q.y; v2 = q.z; v3 = q.w;
    } else {
        if (base     < M) v0 = cnt[base];
        if (base + 1 < M) v1 = cnt[base + 1];
        if (base + 2 < M) v2 = cnt[base + 2];
        if (base + 3 < M) v3 = cnt[base + 3];
    }
    const int s = v0 + v1 + v2 + v3;
    const int lane = t & 63;
    int inc = s;
    #pragma unroll
    for (int off = 1; off < 64; off <<= 1) {
        const int u = __shfl_up(inc, off, 64);
        if (lane >= off) inc += u;
    }
    __shared__ int wsum[4];
    if (lane == 63) wsum[t >> 6] = inc;
    __syncthreads();
    int wpre = 0;
    const int w = t >> 6;
    for (int i = 0; i < w; ++i) wpre += wsum[i];
    int run = bpre + wpre + (inc - s);   // exclusive prefix
    const int vv[4] = {v0, v1, v2, v3};
    #pragma unroll
    for (int i = 0; i < 4; ++i) {
        const int g = base + i;
        if (g < M) {
            if (g < N) row_in[g] = run; else row_out[g - N] = run;
            cnt[g] = run;
            run += vv[i];
        }
    }
    if (blockIdx.x == 0 && t == 0) { row_in[N] = E; row_out[N] = 2 * E; }
}

// Fill CSR entries with the gate PACKED alongside the index: idx2[e] = {node*4+label, bits(gate)}.
__global__ __launch_bounds__(256) void sgcn_fill(
    const int* __restrict__ ei, const int* __restrict__ lab,
    const float* __restrict__ sg_in, const float* __restrict__ sg_out,
    int* __restrict__ fill, int2* __restrict__ idx2, int N, int E)
{
    const int e = blockIdx.x * blockDim.x + threadIdx.x;
    if (e < E) {
        const int s = ei[e];
        const int d = ei[E + e];
        const int l = lab[e];
        const int pi = atomicAdd(fill + d, 1);        // in [0, E)
        idx2[pi] = make_int2(s * 4 + l, __float_as_int(sg_in[(size_t)s * 4 + l]));
        const int po = atomicAdd(fill + N + s, 1);    // in [E, 2E)
        idx2[po] = make_int2(d * 4 + l, __float_as_int(sg_out[(size_t)d * 4 + l]));
    }
}

// Phase 2 (CSR): one wave per node, 4 edge-groups of 16 lanes, PAIRED (depth-2)
// loads per trip: both idx2 entries then both h rows issued together -> 2 random
// reads in flight per group (8 per wave) with no extra lanes.
// Invalid second slot = dummy row 0 with g=0 (exact no-op, label 0 adds 0.0).
__global__ __launch_bounds__(256) void sgcn_gather4p(
    const unsigned short* __restrict__ h_in, const unsigned short* __restrict__ h_out,
    const int* __restrict__ row_in, const int* __restrict__ row_out,
    const int2* __restrict__ idx2,
    const float* __restrict__ b_in, const float* __restrict__ b_out,
    float* __restrict__ out, int N)
{
    const int lane = threadIdx.x & 63;
    const int node = (int)((blockIdx.x * (unsigned)blockDim.x + threadIdx.x) >> 6);
    if (node >= N) return;
    const int sub = lane >> 4;      // edge group 0..3
    const int sl  = lane & 15;      // 16 lanes x 8 cols = 128 cols
    const int cb  = sl * 8;

    // hoist all four bounds so both loops' ranges are in flight early
    const int ri0 = row_in[node],  ri1 = row_in[node + 1];
    const int ro0 = row_out[node], ro1 = row_out[node + 1];

    float acc[8];
    #pragma unroll
    for (int j = 0; j < 8; ++j) acc[j] = 0.f;
    float gi0 = 0.f, gi1 = 0.f, gi2 = 0.f, gi3 = 0.f;
    float go0 = 0.f, go1 = 0.f, go2 = 0.f, go3 = 0.f;

    for (int e = ri0 + sub; e < ri1; e += 8) {
        const int2 pa = idx2[e];
        const bool bv = (e + 4) < ri1;
        const int2 pb = bv ? idx2[e + 4] : make_int2(0, 0);   // g bits = 0 -> 0.0f
        const u16x8 ha = *(const u16x8*)(h_in + (size_t)(pa.x >> 2) * 128 + cb);
        const u16x8 hb = *(const u16x8*)(h_in + (size_t)(pb.x >> 2) * 128 + cb);
        const float ga = __int_as_float(pa.y);
        const float gb = __int_as_float(pb.y);
        const int la = pa.x & 3, lb = pb.x & 3;
        gi0 += ((la == 0) ? ga : 0.f) + ((lb == 0) ? gb : 0.f);
        gi1 += ((la == 1) ? ga : 0.f) + ((lb == 1) ? gb : 0.f);
        gi2 += ((la == 2) ? ga : 0.f) + ((lb == 2) ? gb : 0.f);
        gi3 += ((la == 3) ? ga : 0.f) + ((lb == 3) ? gb : 0.f);
        #pragma unroll
        for (int j = 0; j < 8; ++j)
            acc[j] = fmaf(gb, b2f(hb[j]), fmaf(ga, b2f(ha[j]), acc[j]));
    }

    for (int e = ro0 + sub; e < ro1; e += 8) {
        const int2 pa = idx2[e];
        const bool bv = (e + 4) < ro1;
        const int2 pb = bv ? idx2[e + 4] : make_int2(0, 0);
        const u16x8 ha = *(const u16x8*)(h_out + (size_t)(pa.x >> 2) * 128 + cb);
        const u16x8 hb = *(const u16x8*)(h_out + (size_t)(pb.x >> 2) * 128 + cb);
        const float ga = __int_as_float(pa.y);
        const float gb = __int_as_float(pb.y);
        const int la = pa.x & 3, lb = pb.x & 3;
        go0 += ((la == 0) ? ga : 0.f) + ((lb == 0) ? gb : 0.f);
        go1 += ((la == 1) ? ga : 0.f) + ((lb == 1) ? gb : 0.f);
        go2 += ((la == 2) ? ga : 0.f) + ((lb == 2) ? gb : 0.f);
        go3 += ((la == 3) ? ga : 0.f) + ((lb == 3) ? gb : 0.f);
        #pragma unroll
        for (int j = 0; j < 8; ++j)
            acc[j] = fmaf(gb, b2f(hb[j]), fmaf(ga, b2f(ha[j]), acc[j]));
    }

    // combine the 4 edge groups (lanes l, l^16, l^32, l^48 share the same cols)
    #pragma unroll
    for (int j = 0; j < 8; ++j) {
        acc[j] += __shfl_xor(acc[j], 16, 64);
        acc[j] += __shfl_xor(acc[j], 32, 64);
    }
    gi0 += __shfl_xor(gi0, 16, 64); gi0 += __shfl_xor(gi0, 32, 64);
    gi1 += __shfl_xor(gi1, 16, 64); gi1 += __shfl_xor(gi1, 32, 64);
    gi2 += __shfl_xor(gi2, 16, 64); gi2 += __shfl_xor(gi2, 32, 64);
    gi3 += __shfl_xor(gi3, 16, 64); gi3 += __shfl_xor(gi3, 32, 64);
    go0 += __shfl_xor(go0, 16, 64); go0 += __shfl_xor(go0, 32, 64);
    go1 += __shfl_xor(go1, 16, 64); go1 += __shfl_xor(go1, 32, 64);
    go2 += __shfl_xor(go2, 16, 64); go2 += __shfl_xor(go2, 32, 64);
    go3 += __shfl_xor(go3, 16, 64); go3 += __shfl_xor(go3, 32, 64);

    if (sub == 0) {
        const float gis[4] = {gi0, gi1, gi2, gi3};
        const float gos[4] = {go0, go1, go2, go3};
        #pragma unroll
        for (int l = 0; l < 4; ++l) {
            const float4 bi0 = *(const float4*)(b_in + l * 128 + cb);
            const float4 bi1 = *(const float4*)(b_in + l * 128 + cb + 4);
            const float4 bo0 = *(const float4*)(b_out + l * 128 + cb);
            const float4 bo1 = *(const float4*)(b_out + l * 128 + cb + 4);
            acc[0] = fmaf(gis[l], bi0.x, fmaf(gos[l], bo0.x, acc[0]));
            acc[1] = fmaf(gis[l], bi0.y, fmaf(gos[l], bo0.y, acc[1]));
            acc[2] = fmaf(gis[l], bi0.z, fmaf(gos[l], bo0.z, acc[2]));
            acc[3] = fmaf(gis[l], bi0.w, fmaf(gos[l], bo0.w, acc[3]));
            acc[4] = fmaf(gis[l], bi1.x, fmaf(gos[l], bo1.x, acc[4]));
            acc[5] = fmaf(gis[l], bi1.y, fmaf(gos[l], bo1.y, acc[5]));
            acc[6] = fmaf(gis[l], bi1.z, fmaf(gos[l], bo1.z, acc[6]));
            acc[7] = fmaf(gis[l], bi1.w, fmaf(gos[l], bo1.w, acc[7]));
        }
        float* orow = out + (size_t)node * 128 + cb;
        float4 o0 = *(const float4*)orow;
        float4 o1 = *(const float4*)(orow + 4);
        o0.x = fmaxf(o0.x + acc[0], 0.f); o0.y = fmaxf(o0.y + acc[1], 0.f);
        o0.z = fmaxf(o0.z + acc[2], 0.f); o0.w = fmaxf(o0.w + acc[3], 0.f);
        o1.x = fmaxf(o1.x + acc[4], 0.f); o1.y = fmaxf(o1.y + acc[5], 0.f);
        o1.z = fmaxf(o1.z + acc[6], 0.f); o1.w = fmaxf(o1.w + acc[7], 0.f);
        *(float4*)orow = o0;
        *(float4*)(orow + 4) = o1;
    }
}

// ---------- fallback (atomic path) ----------
__global__ __launch_bounds__(256) void sgcn_scatter(
    const unsigned short* __restrict__ h_in, const unsigned short* __restrict__ h_out,
    const float* __restrict__ sg_in, const float* __restrict__ sg_out,
    const int* __restrict__ ei, const int* __restrict__ lab,
    const float* __restrict__ b_in, const float* __restrict__ b_out,
    float* __restrict__ out, int E)
{
    const int lane = threadIdx.x & 63;
    const int wid = (blockIdx.x * blockDim.x + threadIdx.x) >> 6;
    const int nw = (gridDim.x * blockDim.x) >> 6;
    const int c = lane * 2;

    for (int e = wid; e < E; e += nw) {
        const int s = ei[e];
        const int d = ei[E + e];
        const int l = lab[e];
        {
            const ushort2 hv = *(const ushort2*)(h_in + (size_t)s * 128 + c);
            const float2 bv = *(const float2*)(b_in + l * 128 + c);
            const float g = sg_in[(size_t)s * 4 + l];
            atomicAdd(out + (size_t)d * 128 + c,     g * (b2f(hv.x) + bv.x));
            atomicAdd(out + (size_t)d * 128 + c + 1, g * (b2f(hv.y) + bv.y));
        }
        {
            const ushort2 hv = *(const ushort2*)(h_out + (size_t)d * 128 + c);
            const float2 bv = *(const float2*)(b_out + l * 128 + c);
            const float g = sg_out[(size_t)d * 4 + l];
            atomicAdd(out + (size_t)s * 128 + c,     g * (b2f(hv.x) + bv.x));
            atomicAdd(out + (size_t)s * 128 + c + 1, g * (b2f(hv.y) + bv.y));
        }
    }
}

__global__ __launch_bounds__(256) void sgcn_relu(float* __restrict__ out, long total4)
{
    const long i = (long)blockIdx.x * blockDim.x + threadIdx.x;
    if (i < total4) {
        float4 v = ((float4*)out)[i];
        v.x = fmaxf(v.x, 0.f); v.y = fmaxf(v.y, 0.f);
        v.z = fmaxf(v.z, 0.f); v.w = fmaxf(v.w, 0.f);
        ((float4*)out)[i] = v;
    }
}

extern "C" void kernel_launch(void* const* d_in, const int* in_sizes, int n_in,
                              void* d_out, int out_size, void* d_ws, size_t ws_size,
                              hipStream_t stream)
{
    const float* x        = (const float*)d_in[0];
    const int*   ei       = (const int*)d_in[1];
    const int*   lab      = (const int*)d_in[2];
    const float* W_loop   = (const float*)d_in[3];
    const float* b_loop   = (const float*)d_in[4];
    const float* W_loop_g = (const float*)d_in[5];
    const float* b_loop_g = (const float*)d_in[6];
    const float* W_in     = (const float*)d_in[7];
    const float* b_in     = (const float*)d_in[8];
    const float* W_in_g   = (const float*)d_in[9];
    const float* b_in_g   = (const float*)d_in[10];
    const float* W_out    = (const float*)d_in[11];
    const float* b_out    = (const float*)d_in[12];
    const float* W_out_g  = (const float*)d_in[13];
    const float* b_out_g  = (const float*)d_in[14];

    const int N = in_sizes[0] / 128;
    const int E = in_sizes[1] / 2;
    const int M = 2 * N;
    const int B = (M + 1023) / 1024;

    unsigned short* h_in  = (unsigned short*)d_ws;            // N*128 bf16
    unsigned short* h_out = h_in + (size_t)N * 128;           // N*128 bf16
    float* sg_in  = (float*)(h_out + (size_t)N * 128);        // N*4
    float* sg_out = sg_in + (size_t)N * 4;                    // N*4
    unsigned short* Wt = (unsigned short*)(sg_out + (size_t)N * 4);  // 3*16384 bf16
    int* row_in  = (int*)(Wt + 3 * 16384);                    // N+1
    int* row_out = row_in + (N + 1);                          // N+1
    int* cnt     = row_out + (N + 1);                         // 2N
    int* bsum    = cnt + M;                                   // B
    int2* idx2   = (int2*)(((size_t)(bsum + B) + 15) & ~(size_t)15);  // 2E int2
    const size_t need = ((size_t)(idx2 + 2 * (size_t)E) - (size_t)d_ws);

    float* out = (float*)d_out;
    dim3 blk(256);
    const bool csr = (need <= ws_size);

    if (csr) hipMemsetAsync(cnt, 0, (size_t)M * sizeof(int), stream);

    const int E_hist = csr ? E : 0;
    const int hist_blocks = csr ? (E + 255) / 256 : 0;
    prep_hist<<<dim3(192 + hist_blocks), blk, 0, stream>>>(
        W_in, W_out, W_loop, Wt, ei, cnt, N, E_hist, E);

    sgcn_node_mfma<<<dim3((N + 127) / 128), blk, 0, stream>>>(
        x, Wt, b_loop, W_loop_g, b_loop_g, W_in_g, b_in_g, W_out_g, b_out_g,
        h_in, h_out, sg_in, sg_out, out, N);

    if (csr) {
        scan_partial<<<dim3(B), blk, 0, stream>>>(cnt, bsum, M);
        scan_final<<<dim3(B), blk, 0, stream>>>(cnt, bsum, row_in, row_out, N, E);
        sgcn_fill<<<dim3((E + 255) / 256), blk, 0, stream>>>(
            ei, lab, sg_in, sg_out, cnt, idx2, N, E);
        sgcn_gather4p<<<dim3((N * 64 + 255) / 256), blk, 0, stream>>>(
            h_in, h_out, row_in, row_out, idx2, b_in, b_out, out, N);
    } else {
        sgcn_scatter<<<dim3(2048), blk, 0, stream>>>(
            h_in, h_out, sg_in, sg_out, ei, lab, b_in, b_out, out, E);
        const long total4 = (long)N * 128 / 4;
        sgcn_relu<<<dim3((unsigned)((total4 + 255) / 256)), blk, 0, stream>>>(out, total4);
    }
}

// Round 14
// 290.531 us; speedup vs baseline: 1.2857x; 1.0038x over previous
//
#include <hip/hip_runtime.h>
#include <math.h>

typedef float  f32x4  __attribute__((ext_vector_type(4)));
typedef short  bf16x8 __attribute__((ext_vector_type(8)));
typedef unsigned short u16x8 __attribute__((ext_vector_type(8)));

#define XROW 136   // padded LDS row stride in bf16 elems (272 B): breaks 32-way bank conflict
#define HROW 132   // hbuf row stride: 2*132 % 64B -> lk-groups partition all 32 banks exactly

__device__ __forceinline__ float sigmoidf_(float v) {
    return 1.f / (1.f + __expf(-v));
}
__device__ __forceinline__ unsigned short f2b(float f) {
    union { float f; unsigned u; } c; c.f = f;
    const unsigned r = c.u + 0x7FFF + ((c.u >> 16) & 1);   // round-to-nearest-even
    return (unsigned short)(r >> 16);
}
__device__ __forceinline__ float b2f(unsigned short u) {
    union { unsigned u; float f; } c; c.u = ((unsigned)u) << 16;
    return c.f;
}

// Fused prep: blocks [0,192) convert W to bf16 Wt[m][n][k]; blocks >=192 histogram degrees.
__global__ __launch_bounds__(256) void prep_hist(
    const float* __restrict__ Win, const float* __restrict__ Wout,
    const float* __restrict__ Wloop, unsigned short* __restrict__ Wt,
    const int* __restrict__ ei, int* __restrict__ cnt, int N, int E_hist, int E)
{
    if (blockIdx.x < 192) {
        const int t = blockIdx.x * 256 + threadIdx.x;
        if (t >= 3 * 16384) return;
        const int m = t >> 14;
        const int i = t & 16383;           // k*128 + n (coalesced read)
        const int k = i >> 7, n = i & 127;
        const float* W = (m == 0) ? Win : ((m == 1) ? Wout : Wloop);
        Wt[m * 16384 + n * 128 + k] = f2b(W[i]);
    } else {
        const int e = (blockIdx.x - 192) * 256 + threadIdx.x;
        if (e < E_hist) {
            atomicAdd(cnt + ei[E + e], 1);       // in-direction keyed by dst
            atomicAdd(cnt + N + ei[e], 1);       // out-direction keyed by src
        }
    }
}

// Phase 1 (MFMA): 128 nodes/block, 4 waves, 32 nodes/wave.
// h phases store via per-wave LDS transpose -> coalesced u16x8 global stores.
__global__ __launch_bounds__(256) void sgcn_node_mfma(
    const float* __restrict__ x,
    const unsigned short* __restrict__ Wt,
    const float* __restrict__ b_loop,
    const float* __restrict__ W_loop_g, const float* __restrict__ b_loop_g,
    const float* __restrict__ W_in_g, const float* __restrict__ b_in_g,
    const float* __restrict__ W_out_g, const float* __restrict__ b_out_g,
    unsigned short* __restrict__ h_in, unsigned short* __restrict__ h_out,
    float* __restrict__ sg_in, float* __restrict__ sg_out,
    float* __restrict__ out, int N)
{
    __shared__ unsigned short xs[128 * XROW];     // ~34.8 KB
    __shared__ unsigned short hbuf[4 * 16 * HROW]; // ~16.9 KB, per-wave 16x128 transpose
    __shared__ float gls[128];
    const int tid = threadIdx.x;
    const int n0 = blockIdx.x * 128;

    {
        const int row = tid >> 1;
        const int cb = (tid & 1) * 64;
        unsigned short* dst = &xs[row * XROW + cb];
        const int n = n0 + row;
        if (n < N) {
            const float* xr = x + (size_t)n * 128 + cb;
            #pragma unroll
            for (int i = 0; i < 64; i += 8) {
                const float4 v0 = *(const float4*)(xr + i);
                const float4 v1 = *(const float4*)(xr + i + 4);
                u16x8 pk;
                pk[0] = f2b(v0.x); pk[1] = f2b(v0.y); pk[2] = f2b(v0.z); pk[3] = f2b(v0.w);
                pk[4] = f2b(v1.x); pk[5] = f2b(v1.y); pk[6] = f2b(v1.z); pk[7] = f2b(v1.w);
                *(u16x8*)(dst + i) = pk;
            }
        } else {
            const u16x8 z = {0,0,0,0,0,0,0,0};
            #pragma unroll
            for (int i = 0; i < 64; i += 8) *(u16x8*)(dst + i) = z;
        }
    }
    __syncthreads();

    if (tid < 128) {
        const int n = n0 + tid;
        if (n < N) {
            float gl = 0.f, gi = 0.f, go = 0.f;
            const unsigned short* xr = &xs[tid * XROW];
            for (int kc = 0; kc < 128; kc += 8) {
                const u16x8 c = *(const u16x8*)(xr + kc);
                #pragma unroll
                for (int j = 0; j < 8; ++j) {
                    const float xv = b2f(c[j]);
                    gl = fmaf(xv, W_loop_g[kc + j], gl);
                    gi = fmaf(xv, W_in_g[kc + j], gi);
                    go = fmaf(xv, W_out_g[kc + j], go);
                }
            }
            gls[tid] = sigmoidf_(gl + b_loop_g[0]);
            #pragma unroll
            for (int l = 0; l < 4; ++l) {
                sg_in[(size_t)n * 4 + l]  = sigmoidf_(gi + b_in_g[l]);
                sg_out[(size_t)n * 4 + l] = sigmoidf_(go + b_out_g[l]);
            }
        } else {
            gls[tid] = 0.f;
        }
    }
    __syncthreads();

    const int w  = tid >> 6;
    const int l  = tid & 63;
    const int lr = l & 15;
    const int lk = l >> 4;
    const int rbase = w * 32;

    const unsigned short* a0p = &xs[(rbase + lr) * XROW + lk * 8];
    const unsigned short* a1p = &xs[(rbase + 16 + lr) * XROW + lk * 8];
    unsigned short* hb = &hbuf[w * 16 * HROW];

    for (int ph = 0; ph < 3; ++ph) {
        const unsigned short* Wp = Wt + (size_t)ph * 16384;
        f32x4 acc[2][8];
        #pragma unroll
        for (int p = 0; p < 2; ++p)
            #pragma unroll
            for (int nt = 0; nt < 8; ++nt)
                acc[p][nt] = (f32x4){0.f, 0.f, 0.f, 0.f};

        #pragma unroll
        for (int ks = 0; ks < 4; ++ks) {
            const bf16x8 a0 = *(const bf16x8*)(a0p + ks * 32);
            const bf16x8 a1 = *(const bf16x8*)(a1p + ks * 32);
            #pragma unroll
            for (int nt = 0; nt < 8; ++nt) {
                const bf16x8 b = *(const bf16x8*)(Wp + (nt * 16 + lr) * 128 + ks * 32 + lk * 8);
                acc[0][nt] = __builtin_amdgcn_mfma_f32_16x16x32_bf16(a0, b, acc[0][nt], 0, 0, 0);
                acc[1][nt] = __builtin_amdgcn_mfma_f32_16x16x32_bf16(a1, b, acc[1][nt], 0, 0, 0);
            }
        }

        if (ph < 2) {
            unsigned short* hp = (ph == 0) ? h_in : h_out;
            #pragma unroll
            for (int p = 0; p < 2; ++p) {
                // dump wave's 16x128 sub-tile into per-wave LDS (conflict-free banks)
                #pragma unroll
                for (int nt = 0; nt < 8; ++nt)
                    #pragma unroll
                    for (int r = 0; r < 4; ++r)
                        hb[(lk * 4 + r) * HROW + nt * 16 + lr] = f2b(acc[p][nt][r]);
                __syncthreads();
                // coalesced readout: 4 lanes per row, u16x8 stores
                const int row16 = l >> 2;      // 0..15
                const int cq = l & 3;
                const int node = n0 + rbase + p * 16 + row16;
                #pragma unroll
                for (int c = 0; c < 4; ++c) {
                    const int col = (cq + c * 4) * 8;
                    const u16x8 v = *(const u16x8*)(hb + row16 * HROW + col);
                    if (node < N) *(u16x8*)(hp + (size_t)node * 128 + col) = v;
                }
                __syncthreads();
            }
        } else {
            #pragma unroll
            for (int p = 0; p < 2; ++p)
                #pragma unroll
                for (int r = 0; r < 4; ++r) {
                    const int node = n0 + rbase + p * 16 + lk * 4 + r;
                    if (node < N) {
                        const float g = gls[rbase + p * 16 + lk * 4 + r];
                        float* row = out + (size_t)node * 128 + lr;
                        #pragma unroll
                        for (int nt = 0; nt < 8; ++nt)
                            row[nt * 16] = g * (acc[p][nt][r] + b_loop[nt * 16 + lr]);
                    }
                }
        }
    }
}

// ---------- hierarchical scan (2 kernels) ----------
__global__ __launch_bounds__(256) void scan_partial(
    const int* __restrict__ cnt, int* __restrict__ bsum, int M)
{
    const int t = threadIdx.x;
    const int base = blockIdx.x * 1024 + t * 4;
    int s = 0;
    if (base + 3 < M) {
        const int4 q = *(const int4*)(cnt + base);
        s = q.x + q.y + q.z + q.w;
    } else {
        for (int i = 0; i < 4; ++i) if (base + i < M) s += cnt[base + i];
    }
    #pragma unroll
    for (int off = 32; off; off >>= 1) s += __shfl_down(s, off, 64);
    __shared__ int red[4];
    if ((t & 63) == 0) red[t >> 6] = s;
    __syncthreads();
    if (t == 0) bsum[blockIdx.x] = red[0] + red[1] + red[2] + red[3];
}

__global__ __launch_bounds__(256) void scan_final(
    int* __restrict__ cnt, const int* __restrict__ bsum,
    int* __restrict__ row_in, int* __restrict__ row_out, int N, int E)
{
    const int t = threadIdx.x;
    int pv = 0;
    for (int i = t; i < blockIdx.x; i += 256) pv += bsum[i];
    #pragma unroll
    for (int off = 32; off; off >>= 1) pv += __shfl_down(pv, off, 64);
    __shared__ int pre4[4];
    if ((t & 63) == 0) pre4[t >> 6] = pv;
    __syncthreads();
    const int bpre = pre4[0] + pre4[1] + pre4[2] + pre4[3];

    const int base = blockIdx.x * 1024 + t * 4;
    const int M = 2 * N;
    int v0 = 0, v1 = 0, v2 = 0, v3 = 0;
    if (base + 3 < M) {
        const int4 q = *(const int4*)(cnt + base);
        v0 = q.x; v1 = q.y; v2 = q.z; v3 = q.w;
    } else {
        if (base     < M) v0 = cnt[base];
        if (base + 1 < M) v1 = cnt[base + 1];
        if (base + 2 < M) v2 = cnt[base + 2];
        if (base + 3 < M) v3 = cnt[base + 3];
    }
    const int s = v0 + v1 + v2 + v3;
    const int lane = t & 63;
    int inc = s;
    #pragma unroll
    for (int off = 1; off < 64; off <<= 1) {
        const int u = __shfl_up(inc, off, 64);
        if (lane >= off) inc += u;
    }
    __shared__ int wsum[4];
    if (lane == 63) wsum[t >> 6] = inc;
    __syncthreads();
    int wpre = 0;
    const int w = t >> 6;
    for (int i = 0; i < w; ++i) wpre += wsum[i];
    int run = bpre + wpre + (inc - s);   // exclusive prefix
    const int vv[4] = {v0, v1, v2, v3};
    #pragma unroll
    for (int i = 0; i < 4; ++i) {
        const int g = base + i;
        if (g < M) {
            if (g < N) row_in[g] = run; else row_out[g - N] = run;
            cnt[g] = run;
            run += vv[i];
        }
    }
    if (blockIdx.x == 0 && t == 0) { row_in[N] = E; row_out[N] = 2 * E; }
}

// Fill CSR entries with the gate PACKED alongside the index: idx2[e] = {node*4+label, bits(gate)}.
__global__ __launch_bounds__(256) void sgcn_fill(
    const int* __restrict__ ei, const int* __restrict__ lab,
    const float* __restrict__ sg_in, const float* __restrict__ sg_out,
    int* __restrict__ fill, int2* __restrict__ idx2, int N, int E)
{
    const int e = blockIdx.x * blockDim.x + threadIdx.x;
    if (e < E) {
        const int s = ei[e];
        const int d = ei[E + e];
        const int l = lab[e];
        const int pi = atomicAdd(fill + d, 1);        // in [0, E)
        idx2[pi] = make_int2(s * 4 + l, __float_as_int(sg_in[(size_t)s * 4 + l]));
        const int po = atomicAdd(fill + N + s, 1);    // in [E, 2E)
        idx2[po] = make_int2(d * 4 + l, __float_as_int(sg_out[(size_t)d * 4 + l]));
    }
}

// Phase 2 (CSR): one wave per node, 4 edge-groups of 16 lanes, PAIRED (depth-2) loads.
// out-row read hoisted above the gather loops (latency hidden under gathers).
__global__ __launch_bounds__(256) void sgcn_gather4p(
    const unsigned short* __restrict__ h_in, const unsigned short* __restrict__ h_out,
    const int* __restrict__ row_in, const int* __restrict__ row_out,
    const int2* __restrict__ idx2,
    const float* __restrict__ b_in, const float* __restrict__ b_out,
    float* __restrict__ out, int N)
{
    const int lane = threadIdx.x & 63;
    const int node = (int)((blockIdx.x * (unsigned)blockDim.x + threadIdx.x) >> 6);
    if (node >= N) return;
    const int sub = lane >> 4;      // edge group 0..3
    const int sl  = lane & 15;      // 16 lanes x 8 cols = 128 cols
    const int cb  = sl * 8;

    const int ri0 = row_in[node],  ri1 = row_in[node + 1];
    const int ro0 = row_out[node], ro1 = row_out[node + 1];

    // hoist the self-loop accumulator read (sub==0 lanes only; in flight during gathers)
    float* orow = out + (size_t)node * 128 + cb;
    float4 o0, o1;
    if (sub == 0) {
        o0 = *(const float4*)orow;
        o1 = *(const float4*)(orow + 4);
    }

    float acc[8];
    #pragma unroll
    for (int j = 0; j < 8; ++j) acc[j] = 0.f;
    float gi0 = 0.f, gi1 = 0.f, gi2 = 0.f, gi3 = 0.f;
    float go0 = 0.f, go1 = 0.f, go2 = 0.f, go3 = 0.f;

    for (int e = ri0 + sub; e < ri1; e += 8) {
        const int2 pa = idx2[e];
        const bool bv = (e + 4) < ri1;
        const int2 pb = bv ? idx2[e + 4] : make_int2(0, 0);   // g bits = 0 -> 0.0f
        const u16x8 ha = *(const u16x8*)(h_in + (size_t)(pa.x >> 2) * 128 + cb);
        const u16x8 hb = *(const u16x8*)(h_in + (size_t)(pb.x >> 2) * 128 + cb);
        const float ga = __int_as_float(pa.y);
        const float gb = __int_as_float(pb.y);
        const int la = pa.x & 3, lb = pb.x & 3;
        gi0 += ((la == 0) ? ga : 0.f) + ((lb == 0) ? gb : 0.f);
        gi1 += ((la == 1) ? ga : 0.f) + ((lb == 1) ? gb : 0.f);
        gi2 += ((la == 2) ? ga : 0.f) + ((lb == 2) ? gb : 0.f);
        gi3 += ((la == 3) ? ga : 0.f) + ((lb == 3) ? gb : 0.f);
        #pragma unroll
        for (int j = 0; j < 8; ++j)
            acc[j] = fmaf(gb, b2f(hb[j]), fmaf(ga, b2f(ha[j]), acc[j]));
    }

    for (int e = ro0 + sub; e < ro1; e += 8) {
        const int2 pa = idx2[e];
        const bool bv = (e + 4) < ro1;
        const int2 pb = bv ? idx2[e + 4] : make_int2(0, 0);
        const u16x8 ha = *(const u16x8*)(h_out + (size_t)(pa.x >> 2) * 128 + cb);
        const u16x8 hb = *(const u16x8*)(h_out + (size_t)(pb.x >> 2) * 128 + cb);
        const float ga = __int_as_float(pa.y);
        const float gb = __int_as_float(pb.y);
        const int la = pa.x & 3, lb = pb.x & 3;
        go0 += ((la == 0) ? ga : 0.f) + ((lb == 0) ? gb : 0.f);
        go1 += ((la == 1) ? ga : 0.f) + ((lb == 1) ? gb : 0.f);
        go2 += ((la == 2) ? ga : 0.f) + ((lb == 2) ? gb : 0.f);
        go3 += ((la == 3) ? ga : 0.f) + ((lb == 3) ? gb : 0.f);
        #pragma unroll
        for (int j = 0; j < 8; ++j)
            acc[j] = fmaf(gb, b2f(hb[j]), fmaf(ga, b2f(ha[j]), acc[j]));
    }

    #pragma unroll
    for (int j = 0; j < 8; ++j) {
        acc[j] += __shfl_xor(acc[j], 16, 64);
        acc[j] += __shfl_xor(acc[j], 32, 64);
    }
    gi0 += __shfl_xor(gi0, 16, 64); gi0 += __shfl_xor(gi0, 32, 64);
    gi1 += __shfl_xor(gi1, 16, 64); gi1 += __shfl_xor(gi1, 32, 64);
    gi2 += __shfl_xor(gi2, 16, 64); gi2 += __shfl_xor(gi2, 32, 64);
    gi3 += __shfl_xor(gi3, 16, 64); gi3 += __shfl_xor(gi3, 32, 64);
    go0 += __shfl_xor(go0, 16, 64); go0 += __shfl_xor(go0, 32, 64);
    go1 += __shfl_xor(go1, 16, 64); go1 += __shfl_xor(go1, 32, 64);
    go2 += __shfl_xor(go2, 16, 64); go2 += __shfl_xor(go2, 32, 64);
    go3 += __shfl_xor(go3, 16, 64); go3 += __shfl_xor(go3, 32, 64);

    if (sub == 0) {
        const float gis[4] = {gi0, gi1, gi2, gi3};
        const float gos[4] = {go0, go1, go2, go3};
        #pragma unroll
        for (int l = 0; l < 4; ++l) {
            const float4 bi0 = *(const float4*)(b_in + l * 128 + cb);
            const float4 bi1 = *(const float4*)(b_in + l * 128 + cb + 4);
            const float4 bo0 = *(const float4*)(b_out + l * 128 + cb);
            const float4 bo1 = *(const float4*)(b_out + l * 128 + cb + 4);
            acc[0] = fmaf(gis[l], bi0.x, fmaf(gos[l], bo0.x, acc[0]));
            acc[1] = fmaf(gis[l], bi0.y, fmaf(gos[l], bo0.y, acc[1]));
            acc[2] = fmaf(gis[l], bi0.z, fmaf(gos[l], bo0.z, acc[2]));
            acc[3] = fmaf(gis[l], bi0.w, fmaf(gos[l], bo0.w, acc[3]));
            acc[4] = fmaf(gis[l], bi1.x, fmaf(gos[l], bo1.x, acc[4]));
            acc[5] = fmaf(gis[l], bi1.y, fmaf(gos[l], bo1.y, acc[5]));
            acc[6] = fmaf(gis[l], bi1.z, fmaf(gos[l], bo1.z, acc[6]));
            acc[7] = fmaf(gis[l], bi1.w, fmaf(gos[l], bo1.w, acc[7]));
        }
        o0.x = fmaxf(o0.x + acc[0], 0.f); o0.y = fmaxf(o0.y + acc[1], 0.f);
        o0.z = fmaxf(o0.z + acc[2], 0.f); o0.w = fmaxf(o0.w + acc[3], 0.f);
        o1.x = fmaxf(o1.x + acc[4], 0.f); o1.y = fmaxf(o1.y + acc[5], 0.f);
        o1.z = fmaxf(o1.z + acc[6], 0.f); o1.w = fmaxf(o1.w + acc[7], 0.f);
        *(float4*)orow = o0;
        *(float4*)(orow + 4) = o1;
    }
}

// ---------- fallback (atomic path) ----------
__global__ __launch_bounds__(256) void sgcn_scatter(
    const unsigned short* __restrict__ h_in, const unsigned short* __restrict__ h_out,
    const float* __restrict__ sg_in, const float* __restrict__ sg_out,
    const int* __restrict__ ei, const int* __restrict__ lab,
    const float* __restrict__ b_in, const float* __restrict__ b_out,
    float* __restrict__ out, int E)
{
    const int lane = threadIdx.x & 63;
    const int wid = (blockIdx.x * blockDim.x + threadIdx.x) >> 6;
    const int nw = (gridDim.x * blockDim.x) >> 6;
    const int c = lane * 2;

    for (int e = wid; e < E; e += nw) {
        const int s = ei[e];
        const int d = ei[E + e];
        const int l = lab[e];
        {
            const ushort2 hv = *(const ushort2*)(h_in + (size_t)s * 128 + c);
            const float2 bv = *(const float2*)(b_in + l * 128 + c);
            const float g = sg_in[(size_t)s * 4 + l];
            atomicAdd(out + (size_t)d * 128 + c,     g * (b2f(hv.x) + bv.x));
            atomicAdd(out + (size_t)d * 128 + c + 1, g * (b2f(hv.y) + bv.y));
        }
        {
            const ushort2 hv = *(const ushort2*)(h_out + (size_t)d * 128 + c);
            const float2 bv = *(const float2*)(b_out + l * 128 + c);
            const float g = sg_out[(size_t)d * 4 + l];
            atomicAdd(out + (size_t)s * 128 + c,     g * (b2f(hv.x) + bv.x));
            atomicAdd(out + (size_t)s * 128 + c + 1, g * (b2f(hv.y) + bv.y));
        }
    }
}

__global__ __launch_bounds__(256) void sgcn_relu(float* __restrict__ out, long total4)
{
    const long i = (long)blockIdx.x * blockDim.x + threadIdx.x;
    if (i < total4) {
        float4 v = ((float4*)out)[i];
        v.x = fmaxf(v.x, 0.f); v.y = fmaxf(v.y, 0.f);
        v.z = fmaxf(v.z, 0.f); v.w = fmaxf(v.w, 0.f);
        ((float4*)out)[i] = v;
    }
}

extern "C" void kernel_launch(void* const* d_in, const int* in_sizes, int n_in,
                              void* d_out, int out_size, void* d_ws, size_t ws_size,
                              hipStream_t stream)
{
    const float* x        = (const float*)d_in[0];
    const int*   ei       = (const int*)d_in[1];
    const int*   lab      = (const int*)d_in[2];
    const float* W_loop   = (const float*)d_in[3];
    const float* b_loop   = (const float*)d_in[4];
    const float* W_loop_g = (const float*)d_in[5];
    const float* b_loop_g = (const float*)d_in[6];
    const float* W_in     = (const float*)d_in[7];
    const float* b_in     = (const float*)d_in[8];
    const float* W_in_g   = (const float*)d_in[9];
    const float* b_in_g   = (const float*)d_in[10];
    const float* W_out    = (const float*)d_in[11];
    const float* b_out    = (const float*)d_in[12];
    const float* W_out_g  = (const float*)d_in[13];
    const float* b_out_g  = (const float*)d_in[14];

    const int N = in_sizes[0] / 128;
    const int E = in_sizes[1] / 2;
    const int M = 2 * N;
    const int B = (M + 1023) / 1024;

    unsigned short* h_in  = (unsigned short*)d_ws;            // N*128 bf16
    unsigned short* h_out = h_in + (size_t)N * 128;           // N*128 bf16
    float* sg_in  = (float*)(h_out + (size_t)N * 128);        // N*4
    float* sg_out = sg_in + (size_t)N * 4;                    // N*4
    unsigned short* Wt = (unsigned short*)(sg_out + (size_t)N * 4);  // 3*16384 bf16
    int* row_in  = (int*)(Wt + 3 * 16384);                    // N+1
    int* row_out = row_in + (N + 1);                          // N+1
    int* cnt     = row_out + (N + 1);                         // 2N
    int* bsum    = cnt + M;                                   // B
    int2* idx2   = (int2*)(((size_t)(bsum + B) + 15) & ~(size_t)15);  // 2E int2
    const size_t need = ((size_t)(idx2 + 2 * (size_t)E) - (size_t)d_ws);

    float* out = (float*)d_out;
    dim3 blk(256);
    const bool csr = (need <= ws_size);

    if (csr) hipMemsetAsync(cnt, 0, (size_t)M * sizeof(int), stream);

    const int E_hist = csr ? E : 0;
    const int hist_blocks = csr ? (E + 255) / 256 : 0;
    prep_hist<<<dim3(192 + hist_blocks), blk, 0, stream>>>(
        W_in, W_out, W_loop, Wt, ei, cnt, N, E_hist, E);

    sgcn_node_mfma<<<dim3((N + 127) / 128), blk, 0, stream>>>(
        x, Wt, b_loop, W_loop_g, b_loop_g, W_in_g, b_in_g, W_out_g, b_out_g,
        h_in, h_out, sg_in, sg_out, out, N);

    if (csr) {
        scan_partial<<<dim3(B), blk, 0, stream>>>(cnt, bsum, M);
        scan_final<<<dim3(B), blk, 0, stream>>>(cnt, bsum, row_in, row_out, N, E);
        sgcn_fill<<<dim3((E + 255) / 256), blk, 0, stream>>>(
            ei, lab, sg_in, sg_out, cnt, idx2, N, E);
        sgcn_gather4p<<<dim3((N * 64 + 255) / 256), blk, 0, stream>>>(
            h_in, h_out, row_in, row_out, idx2, b_in, b_out, out, N);
    } else {
        sgcn_scatter<<<dim3(2048), blk, 0, stream>>>(
            h_in, h_out, sg_in, sg_out, ei, lab, b_in, b_out, out, E);
        const long total4 = (long)N * 128 / 4;
        sgcn_relu<<<dim3((unsigned)((total4 + 255) / 256)), blk, 0, stream>>>(out, total4);
    }
}

// Round 16
// 286.521 us; speedup vs baseline: 1.3037x; 1.0140x over previous
//
#include <hip/hip_runtime.h>
#include <math.h>

typedef float  f32x4  __attribute__((ext_vector_type(4)));
typedef short  bf16x8 __attribute__((ext_vector_type(8)));
typedef unsigned short u16x8 __attribute__((ext_vector_type(8)));

#define XROW 136   // padded LDS row stride in bf16 elems (272 B): breaks 32-way bank conflict
#define GQ   (1.f / 8191.f)

__device__ __forceinline__ float sigmoidf_(float v) {
    return 1.f / (1.f + __expf(-v));
}
__device__ __forceinline__ unsigned short f2b(float f) {
    union { float f; unsigned u; } c; c.f = f;
    const unsigned r = c.u + 0x7FFF + ((c.u >> 16) & 1);   // round-to-nearest-even
    return (unsigned short)(r >> 16);
}
__device__ __forceinline__ float b2f(unsigned short u) {
    union { unsigned u; float f; } c; c.u = ((unsigned)u) << 16;
    return c.f;
}

// Fused prep: blocks [0,192) convert W to bf16 Wt[m][n][k]; blocks >=192 histogram degrees.
__global__ __launch_bounds__(256) void prep_hist(
    const float* __restrict__ Win, const float* __restrict__ Wout,
    const float* __restrict__ Wloop, unsigned short* __restrict__ Wt,
    const int* __restrict__ ei, int* __restrict__ cnt, int N, int E_hist, int E)
{
    if (blockIdx.x < 192) {
        const int t = blockIdx.x * 256 + threadIdx.x;
        if (t >= 3 * 16384) return;
        const int m = t >> 14;
        const int i = t & 16383;           // k*128 + n (coalesced read)
        const int k = i >> 7, n = i & 127;
        const float* W = (m == 0) ? Win : ((m == 1) ? Wout : Wloop);
        Wt[m * 16384 + n * 128 + k] = f2b(W[i]);
    } else {
        const int e = (blockIdx.x - 192) * 256 + threadIdx.x;
        if (e < E_hist) {
            atomicAdd(cnt + ei[E + e], 1);       // in-direction keyed by dst
            atomicAdd(cnt + N + ei[e], 1);       // out-direction keyed by src
        }
    }
}

// Phase 1 (MFMA): 128 nodes/block, 4 waves, 32 nodes/wave.
__global__ __launch_bounds__(256) void sgcn_node_mfma(
    const float* __restrict__ x,
    const unsigned short* __restrict__ Wt,
    const float* __restrict__ b_loop,
    const float* __restrict__ W_loop_g, const float* __restrict__ b_loop_g,
    const float* __restrict__ W_in_g, const float* __restrict__ b_in_g,
    const float* __restrict__ W_out_g, const float* __restrict__ b_out_g,
    unsigned short* __restrict__ h_in, unsigned short* __restrict__ h_out,
    float* __restrict__ sg_in, float* __restrict__ sg_out,
    float* __restrict__ out, int N)
{
    __shared__ unsigned short xs[128 * XROW];   // ~34.8 KB -> 4 blocks/CU
    __shared__ float gls[128];
    const int tid = threadIdx.x;
    const int n0 = blockIdx.x * 128;

    {
        const int row = tid >> 1;
        const int cb = (tid & 1) * 64;
        unsigned short* dst = &xs[row * XROW + cb];
        const int n = n0 + row;
        if (n < N) {
            const float* xr = x + (size_t)n * 128 + cb;
            #pragma unroll
            for (int i = 0; i < 64; i += 8) {
                const float4 v0 = *(const float4*)(xr + i);
                const float4 v1 = *(const float4*)(xr + i + 4);
                u16x8 pk;
                pk[0] = f2b(v0.x); pk[1] = f2b(v0.y); pk[2] = f2b(v0.z); pk[3] = f2b(v0.w);
                pk[4] = f2b(v1.x); pk[5] = f2b(v1.y); pk[6] = f2b(v1.z); pk[7] = f2b(v1.w);
                *(u16x8*)(dst + i) = pk;
            }
        } else {
            const u16x8 z = {0,0,0,0,0,0,0,0};
            #pragma unroll
            for (int i = 0; i < 64; i += 8) *(u16x8*)(dst + i) = z;
        }
    }
    __syncthreads();

    if (tid < 128) {
        const int n = n0 + tid;
        if (n < N) {
            float gl = 0.f, gi = 0.f, go = 0.f;
            const unsigned short* xr = &xs[tid * XROW];
            for (int kc = 0; kc < 128; kc += 8) {
                const u16x8 c = *(const u16x8*)(xr + kc);
                #pragma unroll
                for (int j = 0; j < 8; ++j) {
                    const float xv = b2f(c[j]);
                    gl = fmaf(xv, W_loop_g[kc + j], gl);
                    gi = fmaf(xv, W_in_g[kc + j], gi);
                    go = fmaf(xv, W_out_g[kc + j], go);
                }
            }
            gls[tid] = sigmoidf_(gl + b_loop_g[0]);
            #pragma unroll
            for (int l = 0; l < 4; ++l) {
                sg_in[(size_t)n * 4 + l]  = sigmoidf_(gi + b_in_g[l]);
                sg_out[(size_t)n * 4 + l] = sigmoidf_(go + b_out_g[l]);
            }
        } else {
            gls[tid] = 0.f;
        }
    }
    __syncthreads();

    const int w  = tid >> 6;
    const int l  = tid & 63;
    const int lr = l & 15;
    const int lk = l >> 4;
    const int rbase = w * 32;

    const unsigned short* a0p = &xs[(rbase + lr) * XROW + lk * 8];
    const unsigned short* a1p = &xs[(rbase + 16 + lr) * XROW + lk * 8];

    for (int ph = 0; ph < 3; ++ph) {
        const unsigned short* Wp = Wt + (size_t)ph * 16384;
        f32x4 acc[2][8];
        #pragma unroll
        for (int p = 0; p < 2; ++p)
            #pragma unroll
            for (int nt = 0; nt < 8; ++nt)
                acc[p][nt] = (f32x4){0.f, 0.f, 0.f, 0.f};

        #pragma unroll
        for (int ks = 0; ks < 4; ++ks) {
            const bf16x8 a0 = *(const bf16x8*)(a0p + ks * 32);
            const bf16x8 a1 = *(const bf16x8*)(a1p + ks * 32);
            #pragma unroll
            for (int nt = 0; nt < 8; ++nt) {
                const bf16x8 b = *(const bf16x8*)(Wp + (nt * 16 + lr) * 128 + ks * 32 + lk * 8);
                acc[0][nt] = __builtin_amdgcn_mfma_f32_16x16x32_bf16(a0, b, acc[0][nt], 0, 0, 0);
                acc[1][nt] = __builtin_amdgcn_mfma_f32_16x16x32_bf16(a1, b, acc[1][nt], 0, 0, 0);
            }
        }

        if (ph < 2) {
            unsigned short* hp = (ph == 0) ? h_in : h_out;
            #pragma unroll
            for (int p = 0; p < 2; ++p)
                #pragma unroll
                for (int r = 0; r < 4; ++r) {
                    const int node = n0 + rbase + p * 16 + lk * 4 + r;
                    if (node < N) {
                        unsigned short* row = hp + (size_t)node * 128 + lr;
                        #pragma unroll
                        for (int nt = 0; nt < 8; ++nt)
                            row[nt * 16] = f2b(acc[p][nt][r]);
                    }
                }
        } else {
            #pragma unroll
            for (int p = 0; p < 2; ++p)
                #pragma unroll
                for (int r = 0; r < 4; ++r) {
                    const int node = n0 + rbase + p * 16 + lk * 4 + r;
                    if (node < N) {
                        const float g = gls[rbase + p * 16 + lk * 4 + r];
                        float* row = out + (size_t)node * 128 + lr;
                        #pragma unroll
                        for (int nt = 0; nt < 8; ++nt)
                            row[nt * 16] = g * (acc[p][nt][r] + b_loop[nt * 16 + lr]);
                    }
                }
        }
    }
}

// ---------- hierarchical scan (2 kernels) ----------
__global__ __launch_bounds__(256) void scan_partial(
    const int* __restrict__ cnt, int* __restrict__ bsum, int M)
{
    const int t = threadIdx.x;
    const int base = blockIdx.x * 1024 + t * 4;
    int s = 0;
    if (base + 3 < M) {
        const int4 q = *(const int4*)(cnt + base);
        s = q.x + q.y + q.z + q.w;
    } else {
        for (int i = 0; i < 4; ++i) if (base + i < M) s += cnt[base + i];
    }
    #pragma unroll
    for (int off = 32; off; off >>= 1) s += __shfl_down(s, off, 64);
    __shared__ int red[4];
    if ((t & 63) == 0) red[t >> 6] = s;
    __syncthreads();
    if (t == 0) bsum[blockIdx.x] = red[0] + red[1] + red[2] + red[3];
}

__global__ __launch_bounds__(256) void scan_final(
    int* __restrict__ cnt, const int* __restrict__ bsum,
    int* __restrict__ row_in, int* __restrict__ row_out, int N, int E)
{
    const int t = threadIdx.x;
    int pv = 0;
    for (int i = t; i < blockIdx.x; i += 256) pv += bsum[i];
    #pragma unroll
    for (int off = 32; off; off >>= 1) pv += __shfl_down(pv, off, 64);
    __shared__ int pre4[4];
    if ((t & 63) == 0) pre4[t >> 6] = pv;
    __syncthreads();
    const int bpre = pre4[0] + pre4[1] + pre4[2] + pre4[3];

    const int base = blockIdx.x * 1024 + t * 4;
    const int M = 2 * N;
    int v0 = 0, v1 = 0, v2 = 0, v3 = 0;
    if (base + 3 < M) {
        const int4 q = *(const int4*)(cnt + base);
        v0 = q.x; v1 = q.y; v2 = q.z; v3 = q.w;
    } else {
        if (base     < M) v0 = cnt[base];
        if (base + 1 < M) v1 = cnt[base + 1];
        if (base + 2 < M) v2 = cnt[base + 2];
        if (base + 3 < M) v3 = cnt[base + 3];
    }
    const int s = v0 + v1 + v2 + v3;
    const int lane = t & 63;
    int inc = s;
    #pragma unroll
    for (int off = 1; off < 64; off <<= 1) {
        const int u = __shfl_up(inc, off, 64);
        if (lane >= off) inc += u;
    }
    __shared__ int wsum[4];
    if (lane == 63) wsum[t >> 6] = inc;
    __syncthreads();
    int wpre = 0;
    const int w = t >> 6;
    for (int i = 0; i < w; ++i) wpre += wsum[i];
    int run = bpre + wpre + (inc - s);   // exclusive prefix
    const int vv[4] = {v0, v1, v2, v3};
    #pragma unroll
    for (int i = 0; i < 4; ++i) {
        const int g = base + i;
        if (g < M) {
            if (g < N) row_in[g] = run; else row_out[g - N] = run;
            cnt[g] = run;
            run += vv[i];
        }
    }
    if (blockIdx.x == 0 && t == 0) { row_in[N] = E; row_out[N] = 2 * E; }
}

// Fill CSR entries, 4 BYTES each: {p = node*4+label : 19 bits | gate q13 : 13 bits}.
// p <= 4*N-1 = 399999 < 2^19; gate in (0,1) -> 13-bit fixed point (err <= 6e-5).
__global__ __launch_bounds__(256) void sgcn_fill(
    const int* __restrict__ ei, const int* __restrict__ lab,
    const float* __restrict__ sg_in, const float* __restrict__ sg_out,
    int* __restrict__ fill, unsigned* __restrict__ idx, int N, int E)
{
    const int e = blockIdx.x * blockDim.x + threadIdx.x;
    if (e < E) {
        const int s = ei[e];
        const int d = ei[E + e];
        const int l = lab[e];
        const int pi = atomicAdd(fill + d, 1);        // in [0, E)
        const unsigned qi = (unsigned)__float2int_rn(sg_in[(size_t)s * 4 + l] * 8191.f);
        idx[pi] = (((unsigned)(s * 4 + l)) << 13) | qi;
        const int po = atomicAdd(fill + N + s, 1);    // in [E, 2E)
        const unsigned qo = (unsigned)__float2int_rn(sg_out[(size_t)d * 4 + l] * 8191.f);
        idx[po] = (((unsigned)(d * 4 + l)) << 13) | qo;
    }
}

// Phase 2 (CSR): one wave per node, 4 edge-groups of 16 lanes, PAIRED (depth-2) loads.
// 4-byte packed CSR entries; out-row read hoisted above the gather loops.
__global__ __launch_bounds__(256) void sgcn_gather4p(
    const unsigned short* __restrict__ h_in, const unsigned short* __restrict__ h_out,
    const int* __restrict__ row_in, const int* __restrict__ row_out,
    const unsigned* __restrict__ idx,
    const float* __restrict__ b_in, const float* __restrict__ b_out,
    float* __restrict__ out, int N)
{
    const int lane = threadIdx.x & 63;
    const int node = (int)((blockIdx.x * (unsigned)blockDim.x + threadIdx.x) >> 6);
    if (node >= N) return;
    const int sub = lane >> 4;      // edge group 0..3
    const int sl  = lane & 15;      // 16 lanes x 8 cols = 128 cols
    const int cb  = sl * 8;

    const int ri0 = row_in[node],  ri1 = row_in[node + 1];
    const int ro0 = row_out[node], ro1 = row_out[node + 1];

    // hoist the self-loop accumulator read (sub==0 lanes; latency hides under gathers)
    float* orow = out + (size_t)node * 128 + cb;
    float4 o0, o1;
    if (sub == 0) {
        o0 = *(const float4*)orow;
        o1 = *(const float4*)(orow + 4);
    }

    float acc[8];
    #pragma unroll
    for (int j = 0; j < 8; ++j) acc[j] = 0.f;
    float gi0 = 0.f, gi1 = 0.f, gi2 = 0.f, gi3 = 0.f;
    float go0 = 0.f, go1 = 0.f, go2 = 0.f, go3 = 0.f;

    for (int e = ri0 + sub; e < ri1; e += 8) {
        const unsigned pa = idx[e];
        const bool bv = (e + 4) < ri1;
        const unsigned pb = bv ? idx[e + 4] : 0u;   // q=0 -> g=0, dummy row 0
        const u16x8 ha = *(const u16x8*)(h_in + (size_t)(pa >> 15) * 128 + cb);
        const u16x8 hb = *(const u16x8*)(h_in + (size_t)(pb >> 15) * 128 + cb);
        const float ga = (float)(pa & 8191u) * GQ;
        const float gb = (float)(pb & 8191u) * GQ;
        const int la = (pa >> 13) & 3, lb = (pb >> 13) & 3;
        gi0 += ((la == 0) ? ga : 0.f) + ((lb == 0) ? gb : 0.f);
        gi1 += ((la == 1) ? ga : 0.f) + ((lb == 1) ? gb : 0.f);
        gi2 += ((la == 2) ? ga : 0.f) + ((lb == 2) ? gb : 0.f);
        gi3 += ((la == 3) ? ga : 0.f) + ((lb == 3) ? gb : 0.f);
        #pragma unroll
        for (int j = 0; j < 8; ++j)
            acc[j] = fmaf(gb, b2f(hb[j]), fmaf(ga, b2f(ha[j]), acc[j]));
    }

    for (int e = ro0 + sub; e < ro1; e += 8) {
        const unsigned pa = idx[e];
        const bool bv = (e + 4) < ro1;
        const unsigned pb = bv ? idx[e + 4] : 0u;
        const u16x8 ha = *(const u16x8*)(h_out + (size_t)(pa >> 15) * 128 + cb);
        const u16x8 hb = *(const u16x8*)(h_out + (size_t)(pb >> 15) * 128 + cb);
        const float ga = (float)(pa & 8191u) * GQ;
        const float gb = (float)(pb & 8191u) * GQ;
        const int la = (pa >> 13) & 3, lb = (pb >> 13) & 3;
        go0 += ((la == 0) ? ga : 0.f) + ((lb == 0) ? gb : 0.f);
        go1 += ((la == 1) ? ga : 0.f) + ((lb == 1) ? gb : 0.f);
        go2 += ((la == 2) ? ga : 0.f) + ((lb == 2) ? gb : 0.f);
        go3 += ((la == 3) ? ga : 0.f) + ((lb == 3) ? gb : 0.f);
        #pragma unroll
        for (int j = 0; j < 8; ++j)
            acc[j] = fmaf(gb, b2f(hb[j]), fmaf(ga, b2f(ha[j]), acc[j]));
    }

    #pragma unroll
    for (int j = 0; j < 8; ++j) {
        acc[j] += __shfl_xor(acc[j], 16, 64);
        acc[j] += __shfl_xor(acc[j], 32, 64);
    }
    gi0 += __shfl_xor(gi0, 16, 64); gi0 += __shfl_xor(gi0, 32, 64);
    gi1 += __shfl_xor(gi1, 16, 64); gi1 += __shfl_xor(gi1, 32, 64);
    gi2 += __shfl_xor(gi2, 16, 64); gi2 += __shfl_xor(gi2, 32, 64);
    gi3 += __shfl_xor(gi3, 16, 64); gi3 += __shfl_xor(gi3, 32, 64);
    go0 += __shfl_xor(go0, 16, 64); go0 += __shfl_xor(go0, 32, 64);
    go1 += __shfl_xor(go1, 16, 64); go1 += __shfl_xor(go1, 32, 64);
    go2 += __shfl_xor(go2, 16, 64); go2 += __shfl_xor(go2, 32, 64);
    go3 += __shfl_xor(go3, 16, 64); go3 += __shfl_xor(go3, 32, 64);

    if (sub == 0) {
        const float gis[4] = {gi0, gi1, gi2, gi3};
        const float gos[4] = {go0, go1, go2, go3};
        #pragma unroll
        for (int l = 0; l < 4; ++l) {
            const float4 bi0 = *(const float4*)(b_in + l * 128 + cb);
            const float4 bi1 = *(const float4*)(b_in + l * 128 + cb + 4);
            const float4 bo0 = *(const float4*)(b_out + l * 128 + cb);
            const float4 bo1 = *(const float4*)(b_out + l * 128 + cb + 4);
            acc[0] = fmaf(gis[l], bi0.x, fmaf(gos[l], bo0.x, acc[0]));
            acc[1] = fmaf(gis[l], bi0.y, fmaf(gos[l], bo0.y, acc[1]));
            acc[2] = fmaf(gis[l], bi0.z, fmaf(gos[l], bo0.z, acc[2]));
            acc[3] = fmaf(gis[l], bi0.w, fmaf(gos[l], bo0.w, acc[3]));
            acc[4] = fmaf(gis[l], bi1.x, fmaf(gos[l], bo1.x, acc[4]));
            acc[5] = fmaf(gis[l], bi1.y, fmaf(gos[l], bo1.y, acc[5]));
            acc[6] = fmaf(gis[l], bi1.z, fmaf(gos[l], bo1.z, acc[6]));
            acc[7] = fmaf(gis[l], bi1.w, fmaf(gos[l], bo1.w, acc[7]));
        }
        o0.x = fmaxf(o0.x + acc[0], 0.f); o0.y = fmaxf(o0.y + acc[1], 0.f);
        o0.z = fmaxf(o0.z + acc[2], 0.f); o0.w = fmaxf(o0.w + acc[3], 0.f);
        o1.x = fmaxf(o1.x + acc[4], 0.f); o1.y = fmaxf(o1.y + acc[5], 0.f);
        o1.z = fmaxf(o1.z + acc[6], 0.f); o1.w = fmaxf(o1.w + acc[7], 0.f);
        *(float4*)orow = o0;
        *(float4*)(orow + 4) = o1;
    }
}

// ---------- fallback (atomic path) ----------
__global__ __launch_bounds__(256) void sgcn_scatter(
    const unsigned short* __restrict__ h_in, const unsigned short* __restrict__ h_out,
    const float* __restrict__ sg_in, const float* __restrict__ sg_out,
    const int* __restrict__ ei, const int* __restrict__ lab,
    const float* __restrict__ b_in, const float* __restrict__ b_out,
    float* __restrict__ out, int E)
{
    const int lane = threadIdx.x & 63;
    const int wid = (blockIdx.x * blockDim.x + threadIdx.x) >> 6;
    const int nw = (gridDim.x * blockDim.x) >> 6;
    const int c = lane * 2;

    for (int e = wid; e < E; e += nw) {
        const int s = ei[e];
        const int d = ei[E + e];
        const int l = lab[e];
        {
            const ushort2 hv = *(const ushort2*)(h_in + (size_t)s * 128 + c);
            const float2 bv = *(const float2*)(b_in + l * 128 + c);
            const float g = sg_in[(size_t)s * 4 + l];
            atomicAdd(out + (size_t)d * 128 + c,     g * (b2f(hv.x) + bv.x));
            atomicAdd(out + (size_t)d * 128 + c + 1, g * (b2f(hv.y) + bv.y));
        }
        {
            const ushort2 hv = *(const ushort2*)(h_out + (size_t)d * 128 + c);
            const float2 bv = *(const float2*)(b_out + l * 128 + c);
            const float g = sg_out[(size_t)d * 4 + l];
            atomicAdd(out + (size_t)s * 128 + c,     g * (b2f(hv.x) + bv.x));
            atomicAdd(out + (size_t)s * 128 + c + 1, g * (b2f(hv.y) + bv.y));
        }
    }
}

__global__ __launch_bounds__(256) void sgcn_relu(float* __restrict__ out, long total4)
{
    const long i = (long)blockIdx.x * blockDim.x + threadIdx.x;
    if (i < total4) {
        float4 v = ((float4*)out)[i];
        v.x = fmaxf(v.x, 0.f); v.y = fmaxf(v.y, 0.f);
        v.z = fmaxf(v.z, 0.f); v.w = fmaxf(v.w, 0.f);
        ((float4*)out)[i] = v;
    }
}

extern "C" void kernel_launch(void* const* d_in, const int* in_sizes, int n_in,
                              void* d_out, int out_size, void* d_ws, size_t ws_size,
                              hipStream_t stream)
{
    const float* x        = (const float*)d_in[0];
    const int*   ei       = (const int*)d_in[1];
    const int*   lab      = (const int*)d_in[2];
    const float* W_loop   = (const float*)d_in[3];
    const float* b_loop   = (const float*)d_in[4];
    const float* W_loop_g = (const float*)d_in[5];
    const float* b_loop_g = (const float*)d_in[6];
    const float* W_in     = (const float*)d_in[7];
    const float* b_in     = (const float*)d_in[8];
    const float* W_in_g   = (const float*)d_in[9];
    const float* b_in_g   = (const float*)d_in[10];
    const float* W_out    = (const float*)d_in[11];
    const float* b_out    = (const float*)d_in[12];
    const float* W_out_g  = (const float*)d_in[13];
    const float* b_out_g  = (const float*)d_in[14];

    const int N = in_sizes[0] / 128;
    const int E = in_sizes[1] / 2;
    const int M = 2 * N;
    const int B = (M + 1023) / 1024;

    unsigned short* h_in  = (unsigned short*)d_ws;            // N*128 bf16
    unsigned short* h_out = h_in + (size_t)N * 128;           // N*128 bf16
    float* sg_in  = (float*)(h_out + (size_t)N * 128);        // N*4
    float* sg_out = sg_in + (size_t)N * 4;                    // N*4
    unsigned short* Wt = (unsigned short*)(sg_out + (size_t)N * 4);  // 3*16384 bf16
    int* row_in  = (int*)(Wt + 3 * 16384);                    // N+1
    int* row_out = row_in + (N + 1);                          // N+1
    int* cnt     = row_out + (N + 1);                         // 2N
    int* bsum    = cnt + M;                                   // B
    unsigned* idx = (unsigned*)(((size_t)(bsum + B) + 15) & ~(size_t)15);  // 2E u32
    const size_t need = ((size_t)(idx + 2 * (size_t)E) - (size_t)d_ws);

    float* out = (float*)d_out;
    dim3 blk(256);
    const bool csr = (need <= ws_size) && (N <= (1 << 17));   // p must fit 19 bits

    if (csr) hipMemsetAsync(cnt, 0, (size_t)M * sizeof(int), stream);

    const int E_hist = csr ? E : 0;
    const int hist_blocks = csr ? (E + 255) / 256 : 0;
    prep_hist<<<dim3(192 + hist_blocks), blk, 0, stream>>>(
        W_in, W_out, W_loop, Wt, ei, cnt, N, E_hist, E);

    sgcn_node_mfma<<<dim3((N + 127) / 128), blk, 0, stream>>>(
        x, Wt, b_loop, W_loop_g, b_loop_g, W_in_g, b_in_g, W_out_g, b_out_g,
        h_in, h_out, sg_in, sg_out, out, N);

    if (csr) {
        scan_partial<<<dim3(B), blk, 0, stream>>>(cnt, bsum, M);
        scan_final<<<dim3(B), blk, 0, stream>>>(cnt, bsum, row_in, row_out, N, E);
        sgcn_fill<<<dim3((E + 255) / 256), blk, 0, stream>>>(
            ei, lab, sg_in, sg_out, cnt, idx, N, E);
        sgcn_gather4p<<<dim3((N * 64 + 255) / 256), blk, 0, stream>>>(
            h_in, h_out, row_in, row_out, idx, b_in, b_out, out, N);
    } else {
        sgcn_scatter<<<dim3(2048), blk, 0, stream>>>(
            h_in, h_out, sg_in, sg_out, ei, lab, b_in, b_out, out, E);
        const long total4 = (long)N * 128 / 4;
        sgcn_relu<<<dim3((unsigned)((total4 + 255) / 256)), blk, 0, stream>>>(out, total4);
    }
}

// Round 18
// 282.278 us; speedup vs baseline: 1.3233x; 1.0150x over previous
//
#include <hip/hip_runtime.h>
#include <math.h>

typedef float  f32x4  __attribute__((ext_vector_type(4)));
typedef short  bf16x8 __attribute__((ext_vector_type(8)));
typedef unsigned short u16x8 __attribute__((ext_vector_type(8)));

#define XROW 136   // padded LDS row stride in bf16 elems (272 B): breaks 32-way bank conflict
#define HROW 132   // transpose-buffer row stride (words stride 66): lk-groups partition banks on write
#define GQ   (1.f / 8191.f)

__device__ __forceinline__ float sigmoidf_(float v) {
    return 1.f / (1.f + __expf(-v));
}
__device__ __forceinline__ unsigned short f2b(float f) {
    union { float f; unsigned u; } c; c.f = f;
    const unsigned r = c.u + 0x7FFF + ((c.u >> 16) & 1);   // round-to-nearest-even
    return (unsigned short)(r >> 16);
}
__device__ __forceinline__ float b2f(unsigned short u) {
    union { unsigned u; float f; } c; c.u = ((unsigned)u) << 16;
    return c.f;
}

// Fused prep: blocks [0,192) convert W to bf16 Wt[m][n][k]; blocks >=192 histogram degrees.
__global__ __launch_bounds__(256) void prep_hist(
    const float* __restrict__ Win, const float* __restrict__ Wout,
    const float* __restrict__ Wloop, unsigned short* __restrict__ Wt,
    const int* __restrict__ ei, int* __restrict__ cnt, int N, int E_hist, int E)
{
    if (blockIdx.x < 192) {
        const int t = blockIdx.x * 256 + threadIdx.x;
        if (t >= 3 * 16384) return;
        const int m = t >> 14;
        const int i = t & 16383;           // k*128 + n (coalesced read)
        const int k = i >> 7, n = i & 127;
        const float* W = (m == 0) ? Win : ((m == 1) ? Wout : Wloop);
        Wt[m * 16384 + n * 128 + k] = f2b(W[i]);
    } else {
        const int e = (blockIdx.x - 192) * 256 + threadIdx.x;
        if (e < E_hist) {
            atomicAdd(cnt + ei[E + e], 1);       // in-direction keyed by dst
            atomicAdd(cnt + N + ei[e], 1);       // out-direction keyed by src
        }
    }
}

// Phase 1 (MFMA): 128 nodes/block, 4 waves, 32 nodes/wave.
// h phases: per-wave LDS transpose (NO barriers - buffer is wave-private) -> coalesced
// 16B global stores. out phase already line-coalesced (64B/row per store), kept scalar.
__global__ __launch_bounds__(256) void sgcn_node_mfma(
    const float* __restrict__ x,
    const unsigned short* __restrict__ Wt,
    const float* __restrict__ b_loop,
    const float* __restrict__ W_loop_g, const float* __restrict__ b_loop_g,
    const float* __restrict__ W_in_g, const float* __restrict__ b_in_g,
    const float* __restrict__ W_out_g, const float* __restrict__ b_out_g,
    unsigned short* __restrict__ h_in, unsigned short* __restrict__ h_out,
    float* __restrict__ sg_in, float* __restrict__ sg_out,
    float* __restrict__ out, int N)
{
    __shared__ unsigned short xs[128 * XROW];       // ~34.8 KB
    __shared__ unsigned short hbuf[4][16 * HROW];   // ~16.9 KB, per-wave private
    __shared__ float gls[128];
    const int tid = threadIdx.x;
    const int n0 = blockIdx.x * 128;

    {
        const int row = tid >> 1;
        const int cb = (tid & 1) * 64;
        unsigned short* dst = &xs[row * XROW + cb];
        const int n = n0 + row;
        if (n < N) {
            const float* xr = x + (size_t)n * 128 + cb;
            #pragma unroll
            for (int i = 0; i < 64; i += 8) {
                const float4 v0 = *(const float4*)(xr + i);
                const float4 v1 = *(const float4*)(xr + i + 4);
                u16x8 pk;
                pk[0] = f2b(v0.x); pk[1] = f2b(v0.y); pk[2] = f2b(v0.z); pk[3] = f2b(v0.w);
                pk[4] = f2b(v1.x); pk[5] = f2b(v1.y); pk[6] = f2b(v1.z); pk[7] = f2b(v1.w);
                *(u16x8*)(dst + i) = pk;
            }
        } else {
            const u16x8 z = {0,0,0,0,0,0,0,0};
            #pragma unroll
            for (int i = 0; i < 64; i += 8) *(u16x8*)(dst + i) = z;
        }
    }
    __syncthreads();

    if (tid < 128) {
        const int n = n0 + tid;
        if (n < N) {
            float gl = 0.f, gi = 0.f, go = 0.f;
            const unsigned short* xr = &xs[tid * XROW];
            for (int kc = 0; kc < 128; kc += 8) {
                const u16x8 c = *(const u16x8*)(xr + kc);
                #pragma unroll
                for (int j = 0; j < 8; ++j) {
                    const float xv = b2f(c[j]);
                    gl = fmaf(xv, W_loop_g[kc + j], gl);
                    gi = fmaf(xv, W_in_g[kc + j], gi);
                    go = fmaf(xv, W_out_g[kc + j], go);
                }
            }
            gls[tid] = sigmoidf_(gl + b_loop_g[0]);
            #pragma unroll
            for (int l = 0; l < 4; ++l) {
                sg_in[(size_t)n * 4 + l]  = sigmoidf_(gi + b_in_g[l]);
                sg_out[(size_t)n * 4 + l] = sigmoidf_(go + b_out_g[l]);
            }
        } else {
            gls[tid] = 0.f;
        }
    }
    __syncthreads();

    const int w  = tid >> 6;
    const int l  = tid & 63;
    const int lr = l & 15;
    const int lk = l >> 4;
    const int rbase = w * 32;

    const unsigned short* a0p = &xs[(rbase + lr) * XROW + lk * 8];
    const unsigned short* a1p = &xs[(rbase + 16 + lr) * XROW + lk * 8];
    unsigned short* hb = hbuf[w];

    for (int ph = 0; ph < 3; ++ph) {
        const unsigned short* Wp = Wt + (size_t)ph * 16384;
        f32x4 acc[2][8];
        #pragma unroll
        for (int p = 0; p < 2; ++p)
            #pragma unroll
            for (int nt = 0; nt < 8; ++nt)
                acc[p][nt] = (f32x4){0.f, 0.f, 0.f, 0.f};

        #pragma unroll
        for (int ks = 0; ks < 4; ++ks) {
            const bf16x8 a0 = *(const bf16x8*)(a0p + ks * 32);
            const bf16x8 a1 = *(const bf16x8*)(a1p + ks * 32);
            #pragma unroll
            for (int nt = 0; nt < 8; ++nt) {
                const bf16x8 b = *(const bf16x8*)(Wp + (nt * 16 + lr) * 128 + ks * 32 + lk * 8);
                acc[0][nt] = __builtin_amdgcn_mfma_f32_16x16x32_bf16(a0, b, acc[0][nt], 0, 0, 0);
                acc[1][nt] = __builtin_amdgcn_mfma_f32_16x16x32_bf16(a1, b, acc[1][nt], 0, 0, 0);
            }
        }

        if (ph < 2) {
            unsigned short* hp = (ph == 0) ? h_in : h_out;
            #pragma unroll
            for (int p = 0; p < 2; ++p) {
                // dump wave's 16x128 half-tile into wave-private LDS.
                // write banks: rows of lk-group start 8*lk words apart -> 4 groups
                // partition the 32 banks; conflict-free.
                #pragma unroll
                for (int nt = 0; nt < 8; ++nt)
                    #pragma unroll
                    for (int r = 0; r < 4; ++r)
                        hb[(lk * 4 + r) * HROW + nt * 16 + lr] = f2b(acc[p][nt][r]);
                // wave-private: NO __syncthreads; lgkmcnt ordering suffices.
                const int row16 = l >> 2;      // 0..15
                const int cq = l & 3;
                const int node = n0 + rbase + p * 16 + row16;
                if (node < N) {
                    #pragma unroll
                    for (int c = 0; c < 4; ++c) {
                        const int col = (c * 4 + cq) * 8;   // 4 consecutive 16B chunks/row
                        const u16x8 v = *(const u16x8*)(hb + row16 * HROW + col);
                        *(u16x8*)(hp + (size_t)node * 128 + col) = v;
                    }
                }
            }
        } else {
            #pragma unroll
            for (int p = 0; p < 2; ++p)
                #pragma unroll
                for (int r = 0; r < 4; ++r) {
                    const int node = n0 + rbase + p * 16 + lk * 4 + r;
                    if (node < N) {
                        const float g = gls[rbase + p * 16 + lk * 4 + r];
                        float* row = out + (size_t)node * 128 + lr;
                        #pragma unroll
                        for (int nt = 0; nt < 8; ++nt)
                            row[nt * 16] = g * (acc[p][nt][r] + b_loop[nt * 16 + lr]);
                    }
                }
        }
    }
}

// ---------- hierarchical scan (2 kernels) ----------
__global__ __launch_bounds__(256) void scan_partial(
    const int* __restrict__ cnt, int* __restrict__ bsum, int M)
{
    const int t = threadIdx.x;
    const int base = blockIdx.x * 1024 + t * 4;
    int s = 0;
    if (base + 3 < M) {
        const int4 q = *(const int4*)(cnt + base);
        s = q.x + q.y + q.z + q.w;
    } else {
        for (int i = 0; i < 4; ++i) if (base + i < M) s += cnt[base + i];
    }
    #pragma unroll
    for (int off = 32; off; off >>= 1) s += __shfl_down(s, off, 64);
    __shared__ int red[4];
    if ((t & 63) == 0) red[t >> 6] = s;
    __syncthreads();
    if (t == 0) bsum[blockIdx.x] = red[0] + red[1] + red[2] + red[3];
}

__global__ __launch_bounds__(256) void scan_final(
    int* __restrict__ cnt, const int* __restrict__ bsum,
    int* __restrict__ row_in, int* __restrict__ row_out, int N, int E)
{
    const int t = threadIdx.x;
    int pv = 0;
    for (int i = t; i < blockIdx.x; i += 256) pv += bsum[i];
    #pragma unroll
    for (int off = 32; off; off >>= 1) pv += __shfl_down(pv, off, 64);
    __shared__ int pre4[4];
    if ((t & 63) == 0) pre4[t >> 6] = pv;
    __syncthreads();
    const int bpre = pre4[0] + pre4[1] + pre4[2] + pre4[3];

    const int base = blockIdx.x * 1024 + t * 4;
    const int M = 2 * N;
    int v0 = 0, v1 = 0, v2 = 0, v3 = 0;
    if (base + 3 < M) {
        const int4 q = *(const int4*)(cnt + base);
        v0 = q.x; v1 = q.y; v2 = q.z; v3 = q.w;
    } else {
        if (base     < M) v0 = cnt[base];
        if (base + 1 < M) v1 = cnt[base + 1];
        if (base + 2 < M) v2 = cnt[base + 2];
        if (base + 3 < M) v3 = cnt[base + 3];
    }
    const int s = v0 + v1 + v2 + v3;
    const int lane = t & 63;
    int inc = s;
    #pragma unroll
    for (int off = 1; off < 64; off <<= 1) {
        const int u = __shfl_up(inc, off, 64);
        if (lane >= off) inc += u;
    }
    __shared__ int wsum[4];
    if (lane == 63) wsum[t >> 6] = inc;
    __syncthreads();
    int wpre = 0;
    const int w = t >> 6;
    for (int i = 0; i < w; ++i) wpre += wsum[i];
    int run = bpre + wpre + (inc - s);   // exclusive prefix
    const int vv[4] = {v0, v1, v2, v3};
    #pragma unroll
    for (int i = 0; i < 4; ++i) {
        const int g = base + i;
        if (g < M) {
            if (g < N) row_in[g] = run; else row_out[g - N] = run;
            cnt[g] = run;
            run += vv[i];
        }
    }
    if (blockIdx.x == 0 && t == 0) { row_in[N] = E; row_out[N] = 2 * E; }
}

// Fill CSR entries, 4 BYTES each: {p = node*4+label : 19 bits | gate q13 : 13 bits}.
__global__ __launch_bounds__(256) void sgcn_fill(
    const int* __restrict__ ei, const int* __restrict__ lab,
    const float* __restrict__ sg_in, const float* __restrict__ sg_out,
    int* __restrict__ fill, unsigned* __restrict__ idx, int N, int E)
{
    const int e = blockIdx.x * blockDim.x + threadIdx.x;
    if (e < E) {
        const int s = ei[e];
        const int d = ei[E + e];
        const int l = lab[e];
        const int pi = atomicAdd(fill + d, 1);        // in [0, E)
        const unsigned qi = (unsigned)__float2int_rn(sg_in[(size_t)s * 4 + l] * 8191.f);
        idx[pi] = (((unsigned)(s * 4 + l)) << 13) | qi;
        const int po = atomicAdd(fill + N + s, 1);    // in [E, 2E)
        const unsigned qo = (unsigned)__float2int_rn(sg_out[(size_t)d * 4 + l] * 8191.f);
        idx[po] = (((unsigned)(d * 4 + l)) << 13) | qo;
    }
}

// Phase 2 (CSR): one wave per node, 4 edge-groups of 16 lanes, PAIRED (depth-2) loads.
__global__ __launch_bounds__(256) void sgcn_gather4p(
    const unsigned short* __restrict__ h_in, const unsigned short* __restrict__ h_out,
    const int* __restrict__ row_in, const int* __restrict__ row_out,
    const unsigned* __restrict__ idx,
    const float* __restrict__ b_in, const float* __restrict__ b_out,
    float* __restrict__ out, int N)
{
    const int lane = threadIdx.x & 63;
    const int node = (int)((blockIdx.x * (unsigned)blockDim.x + threadIdx.x) >> 6);
    if (node >= N) return;
    const int sub = lane >> 4;      // edge group 0..3
    const int sl  = lane & 15;      // 16 lanes x 8 cols = 128 cols
    const int cb  = sl * 8;

    const int ri0 = row_in[node],  ri1 = row_in[node + 1];
    const int ro0 = row_out[node], ro1 = row_out[node + 1];

    float* orow = out + (size_t)node * 128 + cb;
    float4 o0, o1;
    if (sub == 0) {
        o0 = *(const float4*)orow;
        o1 = *(const float4*)(orow + 4);
    }

    float acc[8];
    #pragma unroll
    for (int j = 0; j < 8; ++j) acc[j] = 0.f;
    float gi0 = 0.f, gi1 = 0.f, gi2 = 0.f, gi3 = 0.f;
    float go0 = 0.f, go1 = 0.f, go2 = 0.f, go3 = 0.f;

    for (int e = ri0 + sub; e < ri1; e += 8) {
        const unsigned pa = idx[e];
        const bool bv = (e + 4) < ri1;
        const unsigned pb = bv ? idx[e + 4] : 0u;   // q=0 -> g=0, dummy row 0
        const u16x8 ha = *(const u16x8*)(h_in + (size_t)(pa >> 15) * 128 + cb);
        const u16x8 hb = *(const u16x8*)(h_in + (size_t)(pb >> 15) * 128 + cb);
        const float ga = (float)(pa & 8191u) * GQ;
        const float gb = (float)(pb & 8191u) * GQ;
        const int la = (pa >> 13) & 3, lb = (pb >> 13) & 3;
        gi0 += ((la == 0) ? ga : 0.f) + ((lb == 0) ? gb : 0.f);
        gi1 += ((la == 1) ? ga : 0.f) + ((lb == 1) ? gb : 0.f);
        gi2 += ((la == 2) ? ga : 0.f) + ((lb == 2) ? gb : 0.f);
        gi3 += ((la == 3) ? ga : 0.f) + ((lb == 3) ? gb : 0.f);
        #pragma unroll
        for (int j = 0; j < 8; ++j)
            acc[j] = fmaf(gb, b2f(hb[j]), fmaf(ga, b2f(ha[j]), acc[j]));
    }

    for (int e = ro0 + sub; e < ro1; e += 8) {
        const unsigned pa = idx[e];
        const bool bv = (e + 4) < ro1;
        const unsigned pb = bv ? idx[e + 4] : 0u;
        const u16x8 ha = *(const u16x8*)(h_out + (size_t)(pa >> 15) * 128 + cb);
        const u16x8 hb = *(const u16x8*)(h_out + (size_t)(pb >> 15) * 128 + cb);
        const float ga = (float)(pa & 8191u) * GQ;
        const float gb = (float)(pb & 8191u) * GQ;
        const int la = (pa >> 13) & 3, lb = (pb >> 13) & 3;
        go0 += ((la == 0) ? ga : 0.f) + ((lb == 0) ? gb : 0.f);
        go1 += ((la == 1) ? ga : 0.f) + ((lb == 1) ? gb : 0.f);
        go2 += ((la == 2) ? ga : 0.f) + ((lb == 2) ? gb : 0.f);
        go3 += ((la == 3) ? ga : 0.f) + ((lb == 3) ? gb : 0.f);
        #pragma unroll
        for (int j = 0; j < 8; ++j)
            acc[j] = fmaf(gb, b2f(hb[j]), fmaf(ga, b2f(ha[j]), acc[j]));
    }

    #pragma unroll
    for (int j = 0; j < 8; ++j) {
        acc[j] += __shfl_xor(acc[j], 16, 64);
        acc[j] += __shfl_xor(acc[j], 32, 64);
    }
    gi0 += __shfl_xor(gi0, 16, 64); gi0 += __shfl_xor(gi0, 32, 64);
    gi1 += __shfl_xor(gi1, 16, 64); gi1 += __shfl_xor(gi1, 32, 64);
    gi2 += __shfl_xor(gi2, 16, 64); gi2 += __shfl_xor(gi2, 32, 64);
    gi3 += __shfl_xor(gi3, 16, 64); gi3 += __shfl_xor(gi3, 32, 64);
    go0 += __shfl_xor(go0, 16, 64); go0 += __shfl_xor(go0, 32, 64);
    go1 += __shfl_xor(go1, 16, 64); go1 += __shfl_xor(go1, 32, 64);
    go2 += __shfl_xor(go2, 16, 64); go2 += __shfl_xor(go2, 32, 64);
    go3 += __shfl_xor(go3, 16, 64); go3 += __shfl_xor(go3, 32, 64);

    if (sub == 0) {
        const float gis[4] = {gi0, gi1, gi2, gi3};
        const float gos[4] = {go0, go1, go2, go3};
        #pragma unroll
        for (int l = 0; l < 4; ++l) {
            const float4 bi0 = *(const float4*)(b_in + l * 128 + cb);
            const float4 bi1 = *(const float4*)(b_in + l * 128 + cb + 4);
            const float4 bo0 = *(const float4*)(b_out + l * 128 + cb);
            const float4 bo1 = *(const float4*)(b_out + l * 128 + cb + 4);
            acc[0] = fmaf(gis[l], bi0.x, fmaf(gos[l], bo0.x, acc[0]));
            acc[1] = fmaf(gis[l], bi0.y, fmaf(gos[l], bo0.y, acc[1]));
            acc[2] = fmaf(gis[l], bi0.z, fmaf(gos[l], bo0.z, acc[2]));
            acc[3] = fmaf(gis[l], bi0.w, fmaf(gos[l], bo0.w, acc[3]));
            acc[4] = fmaf(gis[l], bi1.x, fmaf(gos[l], bo1.x, acc[4]));
            acc[5] = fmaf(gis[l], bi1.y, fmaf(gos[l], bo1.y, acc[5]));
            acc[6] = fmaf(gis[l], bi1.z, fmaf(gos[l], bo1.z, acc[6]));
            acc[7] = fmaf(gis[l], bi1.w, fmaf(gos[l], bo1.w, acc[7]));
        }
        o0.x = fmaxf(o0.x + acc[0], 0.f); o0.y = fmaxf(o0.y + acc[1], 0.f);
        o0.z = fmaxf(o0.z + acc[2], 0.f); o0.w = fmaxf(o0.w + acc[3], 0.f);
        o1.x = fmaxf(o1.x + acc[4], 0.f); o1.y = fmaxf(o1.y + acc[5], 0.f);
        o1.z = fmaxf(o1.z + acc[6], 0.f); o1.w = fmaxf(o1.w + acc[7], 0.f);
        *(float4*)orow = o0;
        *(float4*)(orow + 4) = o1;
    }
}

// ---------- fallback (atomic path) ----------
__global__ __launch_bounds__(256) void sgcn_scatter(
    const unsigned short* __restrict__ h_in, const unsigned short* __restrict__ h_out,
    const float* __restrict__ sg_in, const float* __restrict__ sg_out,
    const int* __restrict__ ei, const int* __restrict__ lab,
    const float* __restrict__ b_in, const float* __restrict__ b_out,
    float* __restrict__ out, int E)
{
    const int lane = threadIdx.x & 63;
    const int wid = (blockIdx.x * blockDim.x + threadIdx.x) >> 6;
    const int nw = (gridDim.x * blockDim.x) >> 6;
    const int c = lane * 2;

    for (int e = wid; e < E; e += nw) {
        const int s = ei[e];
        const int d = ei[E + e];
        const int l = lab[e];
        {
            const ushort2 hv = *(const ushort2*)(h_in + (size_t)s * 128 + c);
            const float2 bv = *(const float2*)(b_in + l * 128 + c);
            const float g = sg_in[(size_t)s * 4 + l];
            atomicAdd(out + (size_t)d * 128 + c,     g * (b2f(hv.x) + bv.x));
            atomicAdd(out + (size_t)d * 128 + c + 1, g * (b2f(hv.y) + bv.y));
        }
        {
            const ushort2 hv = *(const ushort2*)(h_out + (size_t)d * 128 + c);
            const float2 bv = *(const float2*)(b_out + l * 128 + c);
            const float g = sg_out[(size_t)d * 4 + l];
            atomicAdd(out + (size_t)s * 128 + c,     g * (b2f(hv.x) + bv.x));
            atomicAdd(out + (size_t)s * 128 + c + 1, g * (b2f(hv.y) + bv.y));
        }
    }
}

__global__ __launch_bounds__(256) void sgcn_relu(float* __restrict__ out, long total4)
{
    const long i = (long)blockIdx.x * blockDim.x + threadIdx.x;
    if (i < total4) {
        float4 v = ((float4*)out)[i];
        v.x = fmaxf(v.x, 0.f); v.y = fmaxf(v.y, 0.f);
        v.z = fmaxf(v.z, 0.f); v.w = fmaxf(v.w, 0.f);
        ((float4*)out)[i] = v;
    }
}

extern "C" void kernel_launch(void* const* d_in, const int* in_sizes, int n_in,
                              void* d_out, int out_size, void* d_ws, size_t ws_size,
                              hipStream_t stream)
{
    const float* x        = (const float*)d_in[0];
    const int*   ei       = (const int*)d_in[1];
    const int*   lab      = (const int*)d_in[2];
    const float* W_loop   = (const float*)d_in[3];
    const float* b_loop   = (const float*)d_in[4];
    const float* W_loop_g = (const float*)d_in[5];
    const float* b_loop_g = (const float*)d_in[6];
    const float* W_in     = (const float*)d_in[7];
    const float* b_in     = (const float*)d_in[8];
    const float* W_in_g   = (const float*)d_in[9];
    const float* b_in_g   = (const float*)d_in[10];
    const float* W_out    = (const float*)d_in[11];
    const float* b_out    = (const float*)d_in[12];
    const float* W_out_g  = (const float*)d_in[13];
    const float* b_out_g  = (const float*)d_in[14];

    const int N = in_sizes[0] / 128;
    const int E = in_sizes[1] / 2;
    const int M = 2 * N;
    const int B = (M + 1023) / 1024;

    unsigned short* h_in  = (unsigned short*)d_ws;            // N*128 bf16
    unsigned short* h_out = h_in + (size_t)N * 128;           // N*128 bf16
    float* sg_in  = (float*)(h_out + (size_t)N * 128);        // N*4
    float* sg_out = sg_in + (size_t)N * 4;                    // N*4
    unsigned short* Wt = (unsigned short*)(sg_out + (size_t)N * 4);  // 3*16384 bf16
    int* row_in  = (int*)(Wt + 3 * 16384);                    // N+1
    int* row_out = row_in + (N + 1);                          // N+1
    int* cnt     = row_out + (N + 1);                         // 2N
    int* bsum    = cnt + M;                                   // B
    unsigned* idx = (unsigned*)(((size_t)(bsum + B) + 15) & ~(size_t)15);  // 2E u32
    const size_t need = ((size_t)(idx + 2 * (size_t)E) - (size_t)d_ws);

    float* out = (float*)d_out;
    dim3 blk(256);
    const bool csr = (need <= ws_size) && (N <= (1 << 17));   // p must fit 19 bits

    if (csr) hipMemsetAsync(cnt, 0, (size_t)M * sizeof(int), stream);

    const int E_hist = csr ? E : 0;
    const int hist_blocks = csr ? (E + 255) / 256 : 0;
    prep_hist<<<dim3(192 + hist_blocks), blk, 0, stream>>>(
        W_in, W_out, W_loop, Wt, ei, cnt, N, E_hist, E);

    sgcn_node_mfma<<<dim3((N + 127) / 128), blk, 0, stream>>>(
        x, Wt, b_loop, W_loop_g, b_loop_g, W_in_g, b_in_g, W_out_g, b_out_g,
        h_in, h_out, sg_in, sg_out, out, N);

    if (csr) {
        scan_partial<<<dim3(B), blk, 0, stream>>>(cnt, bsum, M);
        scan_final<<<dim3(B), blk, 0, stream>>>(cnt, bsum, row_in, row_out, N, E);
        sgcn_fill<<<dim3((E + 255) / 256), blk, 0, stream>>>(
            ei, lab, sg_in, sg_out, cnt, idx, N, E);
        sgcn_gather4p<<<dim3((N * 64 + 255) / 256), blk, 0, stream>>>(
            h_in, h_out, row_in, row_out, idx, b_in, b_out, out, N);
    } else {
        sgcn_scatter<<<dim3(2048), blk, 0, stream>>>(
            h_in, h_out, sg_in, sg_out, ei, lab, b_in, b_out, out, E);
        const long total4 = (long)N * 128 / 4;
        sgcn_relu<<<dim3((unsigned)((total4 + 255) / 256)), blk, 0, stream>>>(out, total4);
    }
}